// Round 6
// baseline (607.839 us; speedup 1.0000x reference)
//
#include <hip/hip_runtime.h>
#include <cstdint>
#include <cstddef>

#define RN 200000   // nodes per side (NU == NI)
#define NR2 400000  // both sides
#define DIM 64
#define NE 1000000  // edges per relation
#define NB_PR 391   // buckets per relation (512 rows each)
#define NBB 782     // total buckets (go: 0..390, back: 391..781)
#define ET 4096     // edges per sort block
#define NBLK 489    // ceil(2*NE / ET)
#define NBLKP 512   // padded row length of C/Rloc (bucket-major)

typedef __attribute__((ext_vector_type(8))) short short8v;   // 8 x bf16 (4 VGPR)
typedef __attribute__((ext_vector_type(4))) float f32x4;
typedef __attribute__((ext_vector_type(8))) unsigned short us8;

struct Ptrs16 { const void* p[16]; };

__device__ __forceinline__ float bf2f(unsigned short u){
  unsigned int x = ((unsigned int)u) << 16;
  return __builtin_bit_cast(float, x);
}
__device__ __forceinline__ unsigned short f2bf(float f){
  unsigned int x = __builtin_bit_cast(unsigned int, f);
  unsigned int r = x + 0x7fffu + ((x >> 16) & 1u);   // RNE
  return (unsigned short)(r >> 16);
}

// ---- dtype sniffing ----
__global__ __launch_bounds__(256) void detect_k(const unsigned short* emb,
                                                const unsigned int* esrc,
                                                int* flags){
  __shared__ int cnt0, cnt1;
  int t = threadIdx.x;
  if (t == 0){ cnt0 = 0; cnt1 = 0; }
  __syncthreads();
  int c0 = 0, c1 = 0;
  #pragma unroll
  for (int s = 0; s < 4; ++s){
    int i = (t*4 + s) * 14;
    float af = fabsf(bf2f(emb[i]));
    if (af > 0.0009765625f && af < 32.0f) c0++;
    int e = t*4 + s;
    if (esrc[2*e + 1] != 0u) c1++;
  }
  atomicAdd(&cnt0, c0); atomicAdd(&cnt1, c1);
  __syncthreads();
  if (t == 0){
    flags[0] = (cnt0 > 512) ? 1 : 0;
    flags[1] = (cnt1 < 512) ? 1 : 0;
  }
}

__global__ __launch_bounds__(256) void zero_k(int* p, int n){
  int i = blockIdx.x*256 + threadIdx.x;
  if (i < n) p[i] = 0;
}

// ---- canonicalize the 16 small param arrays to fp32 ----
__global__ __launch_bounds__(256) void conv_params_k(Ptrs16 ps, const int* flags, float* out){
  const int offs[17] = {0,12288,12352,24640,24704,36992,37056,49344,49408,49472,
                        49536,49600,49664,49728,49792,49856,49920};
  int i = blockIdx.x*256 + threadIdx.x;
  if (i >= 49920) return;
  int a = 0;
  while (i >= offs[a+1]) ++a;
  int j = i - offs[a];
  float v = flags[0] ? bf2f(((const unsigned short*)ps.p[a])[j])
                     : ((const float*)ps.p[a])[j];
  out[i] = v;
}

// ---- prepack the 4 weight matrices into MFMA fragment order (bf16) ----
// Wp short index = frag_idx*8 + r, frag_idx = (((s*2+t2)*4+c)*4+kg)*16 + c16
__global__ __launch_bounds__(256) void prepack_k(const float* __restrict__ params,
                                                 unsigned short* __restrict__ wpack){
  int i = blockIdx.x*256 + threadIdx.x;
  if (i >= 4*8192) return;
  int m = i >> 13, f = i & 8191;
  const int woff[4] = {0, 12352, 24704, 37056};
  int r   = f & 7;
  int c16 = (f >> 3) & 15;
  int kg  = (f >> 7) & 3;
  int c   = (f >> 9) & 3;
  int t2  = (f >> 11) & 1;
  int s   = (f >> 12) & 1;
  int k = s*64 + t2*32 + kg*8 + r;
  wpack[i] = f2bf(params[woff[m] + k*DIM + c*16 + c16]);
}

// ---- canonicalize both embeddings into union bf16 buffer x1 (users, then items) ----
__global__ __launch_bounds__(256) void conv_emb2_k(const void* uin, const void* iin,
                                                   unsigned short* out,
                                                   const int* flags, int n8){
  int i = blockIdx.x*256 + threadIdx.x;
  if (i >= n8) return;
  int item = (i >= RN*8);
  const void* in = item ? iin : uin;
  int li = item ? i - RN*8 : i;
  us8 o;
  if (flags[0]){
    o = ((const us8*)in)[li];
  } else {
    const float* f = (const float*)in + (size_t)li*8;
    #pragma unroll
    for (int r = 0; r < 8; ++r) o[r] = f2bf(f[r]);
  }
  ((us8*)out)[i] = o;
}

// ==== CSR build: block-local counting sort (validated R5) ====
__global__ __launch_bounds__(256) void pass1_k(const unsigned int* go_dst,
                                               const unsigned int* back_dst,
                                               int* __restrict__ C, int* __restrict__ Rloc,
                                               const int* flags){
  __shared__ int h[1024];
  __shared__ int ps[256];
  int blk = blockIdx.x, t = threadIdx.x;
  #pragma unroll
  for (int q = 0; q < 4; ++q) h[t + q*256] = 0;
  __syncthreads();
  int i64 = flags[1];
  int e0 = blk*ET;
  #pragma unroll
  for (int j = 0; j < 16; ++j){
    int e = e0 + j*256 + t;
    if (e < 2*NE){
      int rel = e >= NE;
      int ei = rel ? e - NE : e;
      const unsigned int* pd = rel ? back_dst : go_dst;
      int d = i64 ? (int)pd[2*ei] : (int)pd[ei];
      int b = (rel ? NB_PR : 0) + (d >> 9);
      atomicAdd(&h[b], 1);
    }
  }
  __syncthreads();
  int c4[4], p4[4]; int s = 0;
  #pragma unroll
  for (int q = 0; q < 4; ++q){ c4[q] = h[t*4 + q]; p4[q] = s; s += c4[q]; }
  ps[t] = s;
  __syncthreads();
  for (int o = 1; o < 256; o <<= 1){
    int x = (t >= o) ? ps[t-o] : 0;
    __syncthreads();
    ps[t] += x;
    __syncthreads();
  }
  int base = (t > 0) ? ps[t-1] : 0;
  #pragma unroll
  for (int q = 0; q < 4; ++q){
    int b = t*4 + q;
    if (b < NBB){
      C[b*NBLKP + blk]    = c4[q];
      Rloc[b*NBLKP + blk] = base + p4[q];
    }
  }
}

__global__ __launch_bounds__(256) void sizes_k(const int* __restrict__ C, int* __restrict__ S){
  int w = blockIdx.x*4 + (threadIdx.x >> 6);
  int lane = threadIdx.x & 63;
  if (w >= NBB) return;
  int sum = 0;
  for (int k = lane; k < NBLK; k += 64) sum += C[w*NBLKP + k];
  #pragma unroll
  for (int o = 32; o > 0; o >>= 1) sum += __shfl_down(sum, o, 64);
  if (lane == 0) S[w] = sum;
}

__global__ __launch_bounds__(1024) void scanS_k(const int* __restrict__ S, int* __restrict__ s0,
                                                int* __restrict__ rs){
  __shared__ int sh[1024];
  int t = threadIdx.x;
  int v = (t < NBB) ? S[t] : 0;
  sh[t] = v;
  __syncthreads();
  for (int o = 1; o < 1024; o <<= 1){
    int x = (t >= o) ? sh[t-o] : 0;
    __syncthreads();
    sh[t] += x;
    __syncthreads();
  }
  if (t < NBB) s0[t] = sh[t] - v;
  if (t == NBB-1){ s0[NBB] = sh[t]; rs[NR2] = 2*NE; }
}

__global__ __launch_bounds__(256) void pass2_k(const unsigned int* go_src, const unsigned int* go_dst,
                                               const unsigned int* back_src, const unsigned int* back_dst,
                                               const int* __restrict__ Rloc,
                                               unsigned int* __restrict__ slab, const int* flags){
  __shared__ int lcur[1024];
  int blk = blockIdx.x, t = threadIdx.x;
  for (int b = t; b < NBB; b += 256) lcur[b] = Rloc[b*NBLKP + blk];
  __syncthreads();
  int i64 = flags[1];
  int e0 = blk*ET;
  #pragma unroll
  for (int j = 0; j < 16; ++j){
    int e = e0 + j*256 + t;
    if (e < 2*NE){
      int rel = e >= NE;
      int ei = rel ? e - NE : e;
      const unsigned int* pd = rel ? back_dst : go_dst;
      const unsigned int* psr = rel ? back_src : go_src;
      int d  = i64 ? (int)pd[2*ei]  : (int)pd[ei];
      int sc = i64 ? (int)psr[2*ei] : (int)psr[ei];
      int b = (rel ? NB_PR : 0) + (d >> 9);
      int r = d & 511;
      int pos = atomicAdd(&lcur[b], 1);
      slab[(size_t)blk*ET + pos] = (unsigned)sc | ((unsigned)r << 18);
    }
  }
}

__global__ __launch_bounds__(512) void buildCSR2_k(const int* __restrict__ C,
                                                   const int* __restrict__ Rloc,
                                                   const int* __restrict__ s0g,
                                                   const unsigned int* __restrict__ slab,
                                                   int* __restrict__ rs, int* __restrict__ col){
  __shared__ int cblk[NBLKP], rblk[NBLKP], off[NBLKP];
  __shared__ int lcnt[512], lsc[512], lcur[512];
  int b = blockIdx.x, t = threadIdx.x;
  cblk[t] = (t < NBLK) ? C[b*NBLKP + t] : 0;
  rblk[t] = (t < NBLK) ? Rloc[b*NBLKP + t] : 0;
  lcnt[t] = 0;
  int v = cblk[t];
  off[t] = v;
  __syncthreads();
  for (int o = 1; o < 512; o <<= 1){
    int x = (t >= o) ? off[t-o] : 0;
    __syncthreads();
    off[t] += x;
    __syncthreads();
  }
  int Sb = off[511];
  int excl = off[t] - v;
  __syncthreads();
  off[t] = excl;
  __syncthreads();
  int s0b = s0g[b];
  int d0 = (b < NB_PR) ? b*512 : RN + (b - NB_PR)*512;
  int relEnd = (b < NB_PR) ? RN : NR2;
  int rows = relEnd - d0; if (rows > 512) rows = 512;
  for (int i = t; i < Sb; i += 512){
    int lo = 0;
    #pragma unroll
    for (int st = 256; st > 0; st >>= 1){
      int nx = lo + st;
      if (nx < 512 && off[nx] <= i) lo = nx;
    }
    unsigned int q = slab[(size_t)lo*ET + rblk[lo] + (i - off[lo])];
    atomicAdd(&lcnt[q >> 18], 1);
  }
  __syncthreads();
  int rv = lcnt[t];
  lsc[t] = rv;
  __syncthreads();
  for (int o = 1; o < 512; o <<= 1){
    int x = (t >= o) ? lsc[t-o] : 0;
    __syncthreads();
    lsc[t] += x;
    __syncthreads();
  }
  int start = lsc[t] - rv;
  lcur[t] = start;
  if (t < rows) rs[d0 + t] = s0b + start;
  __syncthreads();
  for (int i = t; i < Sb; i += 512){
    int lo = 0;
    #pragma unroll
    for (int st = 256; st > 0; st >>= 1){
      int nx = lo + st;
      if (nx < 512 && off[nx] <= i) lo = nx;
    }
    unsigned int q = slab[(size_t)lo*ET + rblk[lo] + (i - off[lo])];
    int r = (int)(q >> 18);
    int p = atomicAdd(&lcur[r], 1);
    col[s0b + p] = (int)(q & 0x3FFFFu);
  }
}

// ==== Fused SpMM + GEMM + BN-stats (R6) ====
// One wave per 16-row output tile. Gather goes through a PRIVATE per-wave LDS
// transpose tile (pad 72 shorts -> conflict-free) -> no __syncthreads in the
// compute path. H = Xd@W[0:64] + Agg@W[64:128] + b; fused sum/sumsq stats.
__global__ __launch_bounds__(256) void fused_k(const int* __restrict__ rs,
                                               const int* __restrict__ col,
                                               const unsigned short* __restrict__ Xg,   // gather base (src side)
                                               const unsigned short* __restrict__ Xd,   // dense rows (dst side)
                                               const unsigned short* __restrict__ Wp,   // prepacked frags
                                               const float* __restrict__ bias,
                                               unsigned short* __restrict__ Hout,
                                               float* __restrict__ stats){
  __shared__ float ls[128];
  __shared__ unsigned short lag[4][16][72];
  int t = threadIdx.x;
  for (int i = t; i < 128; i += 256) ls[i] = 0.0f;
  int w = t >> 6, lane = t & 63;
  int gw = blockIdx.x*4 + w;          // wave-tile id, 0..12499 (exact)
  int c16 = lane & 15, kg = lane >> 4;
  int r0 = gw*16;
  // phase 1: gather + normalize 16 rows into the wave's LDS tile
  for (int r = 0; r < 16; ++r){
    int row = r0 + r;
    int b = __builtin_amdgcn_readfirstlane(rs[row]);
    int e = __builtin_amdgcn_readfirstlane(rs[row+1]);
    float acc = 0.0f;
    for (int i = b; i < e; i += 8){
      int rem = e - i;
      int idx0 = __builtin_nontemporal_load(&col[i]);
      int idx[8]; idx[0] = idx0;
      #pragma unroll
      for (int j = 1; j < 8; ++j)
        idx[j] = (j < rem) ? __builtin_nontemporal_load(&col[i + j]) : idx0;
      float v[8];
      #pragma unroll
      for (int j = 0; j < 8; ++j)
        v[j] = bf2f(Xg[((size_t)(unsigned)idx[j] << 6) + lane]);
      #pragma unroll
      for (int j = 0; j < 8; ++j)
        acc += (j < rem) ? v[j] : 0.0f;
    }
    float nrm = (e > b) ? rsqrtf((float)(e - b)) : 1.0f;
    lag[w][r][lane] = f2bf(acc * nrm);
  }
  // B fragments (prepacked, coalesced 16B loads) + bias
  short8v Bf[2][2][4];
  #pragma unroll
  for (int s = 0; s < 2; ++s)
    #pragma unroll
    for (int t2 = 0; t2 < 2; ++t2)
      #pragma unroll
      for (int c = 0; c < 4; ++c)
        Bf[s][t2][c] = ((const short8v*)Wp)[(((s*2 + t2)*4 + c)*4 + kg)*16 + c16];
  float bc[4];
  #pragma unroll
  for (int c = 0; c < 4; ++c) bc[c] = bias[c*16 + c16];
  // A fragments: k 0..63 from dense Xd, k 64..127 from the LDS agg tile
  const short8v* xd = (const short8v*)Xd;
  size_t ar = (size_t)(r0 + c16);
  short8v A00 = xd[ar*8 + kg];
  short8v A01 = xd[ar*8 + 4 + kg];
  short8v A10 = *(const short8v*)&lag[w][c16][kg*8];
  short8v A11 = *(const short8v*)&lag[w][c16][32 + kg*8];
  f32x4 acc4[4];
  #pragma unroll
  for (int c = 0; c < 4; ++c){ f32x4 z = {bc[c],bc[c],bc[c],bc[c]}; acc4[c] = z; }
  #pragma unroll
  for (int c = 0; c < 4; ++c){
    acc4[c] = __builtin_amdgcn_mfma_f32_16x16x32_bf16(A00, Bf[0][0][c], acc4[c], 0, 0, 0);
    acc4[c] = __builtin_amdgcn_mfma_f32_16x16x32_bf16(A01, Bf[0][1][c], acc4[c], 0, 0, 0);
    acc4[c] = __builtin_amdgcn_mfma_f32_16x16x32_bf16(A10, Bf[1][0][c], acc4[c], 0, 0, 0);
    acc4[c] = __builtin_amdgcn_mfma_f32_16x16x32_bf16(A11, Bf[1][1][c], acc4[c], 0, 0, 0);
  }
  int orow = r0 + kg*4;   // C layout: col = lane&15, row = (lane>>4)*4 + reg [m89]
  float ssum[4], ssq[4];
  #pragma unroll
  for (int c = 0; c < 4; ++c){
    ssum[c] = 0.0f; ssq[c] = 0.0f;
    #pragma unroll
    for (int r = 0; r < 4; ++r){
      float v = acc4[c][r];
      ssum[c] += v; ssq[c] += v*v;
      Hout[(size_t)(orow + r)*DIM + c*16 + c16] = f2bf(v);
    }
  }
  __syncthreads();
  #pragma unroll
  for (int c = 0; c < 4; ++c){
    atomicAdd(&ls[c*16 + c16], ssum[c]);
    atomicAdd(&ls[64 + c*16 + c16], ssq[c]);
  }
  __syncthreads();
  if (t < 128) atomicAdd(&stats[t], ls[t]);
}

// ---- BN finalize for both halves of a layer ----
// stats layout: [0..128) first set (items), [128..256) second set (users)
__global__ __launch_bounds__(128) void bnfin2_k(const float* stats,
                                                const float* gI, const float* beI, float* acI,
                                                const float* gU, const float* beU, float* acU){
  int t = threadIdx.x, j = t & 63;
  const float* st = (t < 64) ? stats : stats + 128;
  float mu  = st[j]    * (1.0f/RN);
  float var = st[64+j] * (1.0f/RN) - mu*mu;
  float inv = rsqrtf(var + 1e-5f);
  if (t < 64){ float a = gI[j]*inv; acI[j] = a; acI[64+j] = beI[j] - mu*a; }
  else       { float a = gU[j]*inv; acU[j] = a; acU[64+j] = beU[j] - mu*a; }
}

// ---- BN + SiLU in-place over the union buffer (users half then items half) ----
__global__ __launch_bounds__(256) void bnapply2_k(unsigned short* H,
                                                  const float* __restrict__ acU,
                                                  const float* __restrict__ acI, int n8){
  int i = blockIdx.x*256 + threadIdx.x;
  if (i >= n8) return;
  const float* ac = (i < RN*8) ? acU : acI;
  us8 v = ((us8*)H)[i];
  int cb = (i*8) & 63;
  #pragma unroll
  for (int r = 0; r < 8; ++r){
    float x = bf2f(v[r]);
    float y = ac[cb+r]*x + ac[64+cb+r];
    float o = y / (1.0f + expf(-y));
    v[r] = f2bf(o);
  }
  ((us8*)H)[i] = v;
}

// ---- BN + SiLU to d_out (union layout matches output layout) ----
__global__ __launch_bounds__(256) void bnout2_k(const unsigned short* __restrict__ H,
                                                const float* __restrict__ acU,
                                                const float* __restrict__ acI,
                                                void* out, const int* __restrict__ flags, int n8){
  int i = blockIdx.x*256 + threadIdx.x;
  if (i >= n8) return;
  const float* ac = (i < RN*8) ? acU : acI;
  us8 v = ((const us8*)H)[i];
  int cb = (i*8) & 63;
  float o[8];
  #pragma unroll
  for (int r = 0; r < 8; ++r){
    float x = bf2f(v[r]);
    float y = ac[cb+r]*x + ac[64+cb+r];
    o[r] = y / (1.0f + expf(-y));
  }
  if (flags[0]){
    unsigned short* ob = (unsigned short*)out + (size_t)i*8;
    us8 wv;
    #pragma unroll
    for (int r = 0; r < 8; ++r) wv[r] = f2bf(o[r]);
    __builtin_nontemporal_store(wv, (us8*)ob);
  } else {
    float* ob = (float*)out + (size_t)i*8;
    f32x4 w0 = {o[0],o[1],o[2],o[3]}, w1 = {o[4],o[5],o[6],o[7]};
    __builtin_nontemporal_store(w0, (f32x4*)ob);
    __builtin_nontemporal_store(w1, (f32x4*)ob + 1);
  }
}

extern "C" void kernel_launch(void* const* d_in, const int* in_sizes, int n_in,
                              void* d_out, int out_size, void* d_ws, size_t ws_size,
                              hipStream_t stream){
  (void)in_sizes; (void)n_in; (void)out_size;
  const void* user_emb = d_in[0];
  const void* item_emb = d_in[1];
  const void* go_src   = d_in[18];
  const void* go_dst   = d_in[19];
  const void* back_src = d_in[20];
  const void* back_dst = d_in[21];

  char* ws = (char*)d_ws;
  size_t off = 0;
  auto alloc = [&](size_t bytes) -> void* {
    void* p = ws + off;
    off += (bytes + 255) & ~((size_t)255);
    return p;
  };
  int*   flags  = (int*)  alloc(64);
  float* params = (float*)alloc((size_t)49920*4);
  unsigned short* wpack = (unsigned short*)alloc((size_t)4*8192*2);
  float* bnac   = (float*)alloc(512*4);
  float* stats  = (float*)alloc(512*4);
  int*   Cmat   = (int*)  alloc((size_t)NBB*NBLKP*4);
  int*   Rloc   = (int*)  alloc((size_t)NBB*NBLKP*4);
  int*   Sbuf   = (int*)  alloc(1024*4);
  int*   s0g    = (int*)  alloc(1024*4);
  int*   rs_all = (int*)  alloc((size_t)(NR2+1)*4);
  int*   col_all= (int*)  alloc((size_t)2*NE*4);
  unsigned short* x1 = (unsigned short*)alloc((size_t)NR2*DIM*2);  // union feats (users,items)
  unsigned short* x2 = (unsigned short*)alloc((size_t)NR2*DIM*2);  // layer-1 output / layer-2 input
  if (off > ws_size) return;  // visible as absmax == 5.8125

  unsigned int* slab = (unsigned int*)x2;  // 8MB alias; slab dead before layer-1 writes x2
  unsigned short* h2 = x1;                 // layer-2 raw output aliases x1 (dead by then)

  int* rs_go = rs_all;
  int* rs_bk = rs_all + RN;
  unsigned short* x1u = x1;                 // users at 0
  unsigned short* x1i = x1 + (size_t)RN*DIM;
  unsigned short* x2u = x2;
  unsigned short* x2i = x2 + (size_t)RN*DIM;

  const int G8A = (NR2*DIM/8)/256;          // 12500
  const int GF  = RN/64;                    // 3125 blocks, 4 wave-tiles each

  float* b_go1 = params + 12288;
  float* b_bk1 = params + 24640;
  float* b_go2 = params + 36992;
  float* b_bk2 = params + 49344;
  float* g1u = params + 49408; float* be1u = params + 49472;
  float* g1i = params + 49536; float* be1i = params + 49600;
  float* g2u = params + 49664; float* be2u = params + 49728;
  float* g2i = params + 49792; float* be2i = params + 49856;

  detect_k<<<1,256,0,stream>>>((const unsigned short*)user_emb, (const unsigned int*)go_src, flags);
  zero_k<<<2,256,0,stream>>>((int*)stats, 512);
  Ptrs16 ps;
  for (int i = 0; i < 16; ++i) ps.p[i] = d_in[2+i];
  conv_params_k<<<196,256,0,stream>>>(ps, flags, params);
  prepack_k<<<128,256,0,stream>>>(params, wpack);
  conv_emb2_k<<<G8A,256,0,stream>>>(user_emb, item_emb, x1, flags, NR2*DIM/8);

  // ---- CSR build (block-local counting sort; validated R5) ----
  pass1_k<<<NBLK,256,0,stream>>>((const unsigned int*)go_dst, (const unsigned int*)back_dst,
                                 Cmat, Rloc, flags);
  sizes_k<<<(NBB+3)/4,256,0,stream>>>(Cmat, Sbuf);
  scanS_k<<<1,1024,0,stream>>>(Sbuf, s0g, rs_all);
  pass2_k<<<NBLK,256,0,stream>>>((const unsigned int*)go_src, (const unsigned int*)go_dst,
                                 (const unsigned int*)back_src, (const unsigned int*)back_dst,
                                 Rloc, slab, flags);
  buildCSR2_k<<<NBB,512,0,stream>>>(Cmat, Rloc, s0g, slab, rs_all, col_all);

  // ---- layer 1 (fused spmm+gemm+stats per relation) ----
  fused_k<<<GF,256,0,stream>>>(rs_go, col_all, x1u, x1i, wpack + 0*8192, b_go1, x2i, stats + 0);
  fused_k<<<GF,256,0,stream>>>(rs_bk, col_all, x1i, x1u, wpack + 1*8192, b_bk1, x2u, stats + 128);
  bnfin2_k<<<1,128,0,stream>>>(stats + 0, g1i, be1i, bnac + 0, g1u, be1u, bnac + 128);
  bnapply2_k<<<G8A,256,0,stream>>>(x2, bnac + 128, bnac + 0, NR2*DIM/8);

  // ---- layer 2 (reads x2, writes raw H into h2 == x1) ----
  fused_k<<<GF,256,0,stream>>>(rs_go, col_all, x2u, x2i, wpack + 2*8192, b_go2,
                               h2 + (size_t)RN*DIM, stats + 256);
  fused_k<<<GF,256,0,stream>>>(rs_bk, col_all, x2i, x2u, wpack + 3*8192, b_bk2,
                               h2, stats + 384);
  bnfin2_k<<<1,128,0,stream>>>(stats + 256, g2i, be2i, bnac + 256, g2u, be2u, bnac + 384);
  bnout2_k<<<G8A,256,0,stream>>>(h2, bnac + 384, bnac + 256, d_out, flags, NR2*DIM/8);
}

// Round 7
// 587.750 us; speedup vs baseline: 1.0342x; 1.0342x over previous
//
#include <hip/hip_runtime.h>
#include <cstdint>
#include <cstddef>

#define RN 200000   // nodes per side (NU == NI)
#define NR2 400000  // both sides
#define DIM 64
#define NE 1000000  // edges per relation
#define NB_PR 391   // buckets per relation (512 rows each)
#define NBB 782     // total buckets (go: 0..390, back: 391..781)
#define ET 4096     // edges per sort block
#define NBLK 489    // ceil(2*NE / ET)
#define NBLKP 512   // padded row length of C/Rloc (bucket-major)

typedef __attribute__((ext_vector_type(8))) short short8v;   // 8 x bf16 (4 VGPR)
typedef __attribute__((ext_vector_type(4))) float f32x4;
typedef __attribute__((ext_vector_type(8))) unsigned short us8;

struct Ptrs16 { const void* p[16]; };

__device__ __forceinline__ float bf2f(unsigned short u){
  unsigned int x = ((unsigned int)u) << 16;
  return __builtin_bit_cast(float, x);
}
__device__ __forceinline__ unsigned short f2bf(float f){
  unsigned int x = __builtin_bit_cast(unsigned int, f);
  unsigned int r = x + 0x7fffu + ((x >> 16) & 1u);   // RNE
  return (unsigned short)(r >> 16);
}

// ---- dtype sniffing ----
__global__ __launch_bounds__(256) void detect_k(const unsigned short* emb,
                                                const unsigned int* esrc,
                                                int* flags){
  __shared__ int cnt0, cnt1;
  int t = threadIdx.x;
  if (t == 0){ cnt0 = 0; cnt1 = 0; }
  __syncthreads();
  int c0 = 0, c1 = 0;
  #pragma unroll
  for (int s = 0; s < 4; ++s){
    int i = (t*4 + s) * 14;
    float af = fabsf(bf2f(emb[i]));
    if (af > 0.0009765625f && af < 32.0f) c0++;
    int e = t*4 + s;
    if (esrc[2*e + 1] != 0u) c1++;
  }
  atomicAdd(&cnt0, c0); atomicAdd(&cnt1, c1);
  __syncthreads();
  if (t == 0){
    flags[0] = (cnt0 > 512) ? 1 : 0;
    flags[1] = (cnt1 < 512) ? 1 : 0;
  }
}

__global__ __launch_bounds__(256) void zero_k(int* p, int n){
  int i = blockIdx.x*256 + threadIdx.x;
  if (i < n) p[i] = 0;
}

// ---- canonicalize the 16 small param arrays to fp32 ----
__global__ __launch_bounds__(256) void conv_params_k(Ptrs16 ps, const int* flags, float* out){
  const int offs[17] = {0,12288,12352,24640,24704,36992,37056,49344,49408,49472,
                        49536,49600,49664,49728,49792,49856,49920};
  int i = blockIdx.x*256 + threadIdx.x;
  if (i >= 49920) return;
  int a = 0;
  while (i >= offs[a+1]) ++a;
  int j = i - offs[a];
  float v = flags[0] ? bf2f(((const unsigned short*)ps.p[a])[j])
                     : ((const float*)ps.p[a])[j];
  out[i] = v;
}

// ---- prepack the 4 weight matrices into MFMA fragment order (bf16) ----
// Wp short index = frag_idx*8 + r, frag_idx = (((s*2+t2)*4+c)*4+kg)*16 + c16
__global__ __launch_bounds__(256) void prepack_k(const float* __restrict__ params,
                                                 unsigned short* __restrict__ wpack){
  int i = blockIdx.x*256 + threadIdx.x;
  if (i >= 4*8192) return;
  int m = i >> 13, f = i & 8191;
  const int woff[4] = {0, 12352, 24704, 37056};
  int r   = f & 7;
  int c16 = (f >> 3) & 15;
  int kg  = (f >> 7) & 3;
  int c   = (f >> 9) & 3;
  int t2  = (f >> 11) & 1;
  int s   = (f >> 12) & 1;
  int k = s*64 + t2*32 + kg*8 + r;
  wpack[i] = f2bf(params[woff[m] + k*DIM + c*16 + c16]);
}

// ---- canonicalize both embeddings into union bf16 buffer x1 (users, then items) ----
__global__ __launch_bounds__(256) void conv_emb2_k(const void* uin, const void* iin,
                                                   unsigned short* out,
                                                   const int* flags, int n8){
  int i = blockIdx.x*256 + threadIdx.x;
  if (i >= n8) return;
  int item = (i >= RN*8);
  const void* in = item ? iin : uin;
  int li = item ? i - RN*8 : i;
  us8 o;
  if (flags[0]){
    o = ((const us8*)in)[li];
  } else {
    const float* f = (const float*)in + (size_t)li*8;
    #pragma unroll
    for (int r = 0; r < 8; ++r) o[r] = f2bf(f[r]);
  }
  ((us8*)out)[i] = o;
}

// ==== CSR build: block-local counting sort (validated R5) ====
__global__ __launch_bounds__(256) void pass1_k(const unsigned int* go_dst,
                                               const unsigned int* back_dst,
                                               int* __restrict__ C, int* __restrict__ Rloc,
                                               const int* flags){
  __shared__ int h[1024];
  __shared__ int ps[256];
  int blk = blockIdx.x, t = threadIdx.x;
  #pragma unroll
  for (int q = 0; q < 4; ++q) h[t + q*256] = 0;
  __syncthreads();
  int i64 = flags[1];
  int e0 = blk*ET;
  #pragma unroll
  for (int j = 0; j < 16; ++j){
    int e = e0 + j*256 + t;
    if (e < 2*NE){
      int rel = e >= NE;
      int ei = rel ? e - NE : e;
      const unsigned int* pd = rel ? back_dst : go_dst;
      int d = i64 ? (int)pd[2*ei] : (int)pd[ei];
      int b = (rel ? NB_PR : 0) + (d >> 9);
      atomicAdd(&h[b], 1);
    }
  }
  __syncthreads();
  int c4[4], p4[4]; int s = 0;
  #pragma unroll
  for (int q = 0; q < 4; ++q){ c4[q] = h[t*4 + q]; p4[q] = s; s += c4[q]; }
  ps[t] = s;
  __syncthreads();
  for (int o = 1; o < 256; o <<= 1){
    int x = (t >= o) ? ps[t-o] : 0;
    __syncthreads();
    ps[t] += x;
    __syncthreads();
  }
  int base = (t > 0) ? ps[t-1] : 0;
  #pragma unroll
  for (int q = 0; q < 4; ++q){
    int b = t*4 + q;
    if (b < NBB){
      C[b*NBLKP + blk]    = c4[q];
      Rloc[b*NBLKP + blk] = base + p4[q];
    }
  }
}

__global__ __launch_bounds__(256) void sizes_k(const int* __restrict__ C, int* __restrict__ S){
  int w = blockIdx.x*4 + (threadIdx.x >> 6);
  int lane = threadIdx.x & 63;
  if (w >= NBB) return;
  int sum = 0;
  for (int k = lane; k < NBLK; k += 64) sum += C[w*NBLKP + k];
  #pragma unroll
  for (int o = 32; o > 0; o >>= 1) sum += __shfl_down(sum, o, 64);
  if (lane == 0) S[w] = sum;
}

__global__ __launch_bounds__(1024) void scanS_k(const int* __restrict__ S, int* __restrict__ s0,
                                                int* __restrict__ rs){
  __shared__ int sh[1024];
  int t = threadIdx.x;
  int v = (t < NBB) ? S[t] : 0;
  sh[t] = v;
  __syncthreads();
  for (int o = 1; o < 1024; o <<= 1){
    int x = (t >= o) ? sh[t-o] : 0;
    __syncthreads();
    sh[t] += x;
    __syncthreads();
  }
  if (t < NBB) s0[t] = sh[t] - v;
  if (t == NBB-1){ s0[NBB] = sh[t]; rs[NR2] = 2*NE; }
}

__global__ __launch_bounds__(256) void pass2_k(const unsigned int* go_src, const unsigned int* go_dst,
                                               const unsigned int* back_src, const unsigned int* back_dst,
                                               const int* __restrict__ Rloc,
                                               unsigned int* __restrict__ slab, const int* flags){
  __shared__ int lcur[1024];
  int blk = blockIdx.x, t = threadIdx.x;
  for (int b = t; b < NBB; b += 256) lcur[b] = Rloc[b*NBLKP + blk];
  __syncthreads();
  int i64 = flags[1];
  int e0 = blk*ET;
  #pragma unroll
  for (int j = 0; j < 16; ++j){
    int e = e0 + j*256 + t;
    if (e < 2*NE){
      int rel = e >= NE;
      int ei = rel ? e - NE : e;
      const unsigned int* pd = rel ? back_dst : go_dst;
      const unsigned int* psr = rel ? back_src : go_src;
      int d  = i64 ? (int)pd[2*ei]  : (int)pd[ei];
      int sc = i64 ? (int)psr[2*ei] : (int)psr[ei];
      int b = (rel ? NB_PR : 0) + (d >> 9);
      int r = d & 511;
      int pos = atomicAdd(&lcur[b], 1);
      slab[(size_t)blk*ET + pos] = (unsigned)sc | ((unsigned)r << 18);
    }
  }
}

// col written in UNION space (+RN for back-relation sources = items)
__global__ __launch_bounds__(512) void buildCSR2_k(const int* __restrict__ C,
                                                   const int* __restrict__ Rloc,
                                                   const int* __restrict__ s0g,
                                                   const unsigned int* __restrict__ slab,
                                                   int* __restrict__ rs, int* __restrict__ col){
  __shared__ int cblk[NBLKP], rblk[NBLKP], off[NBLKP];
  __shared__ int lcnt[512], lsc[512], lcur[512];
  int b = blockIdx.x, t = threadIdx.x;
  cblk[t] = (t < NBLK) ? C[b*NBLKP + t] : 0;
  rblk[t] = (t < NBLK) ? Rloc[b*NBLKP + t] : 0;
  lcnt[t] = 0;
  int v = cblk[t];
  off[t] = v;
  __syncthreads();
  for (int o = 1; o < 512; o <<= 1){
    int x = (t >= o) ? off[t-o] : 0;
    __syncthreads();
    off[t] += x;
    __syncthreads();
  }
  int Sb = off[511];
  int excl = off[t] - v;
  __syncthreads();
  off[t] = excl;
  __syncthreads();
  int s0b = s0g[b];
  int d0 = (b < NB_PR) ? b*512 : RN + (b - NB_PR)*512;
  int relEnd = (b < NB_PR) ? RN : NR2;
  int rows = relEnd - d0; if (rows > 512) rows = 512;
  int srcoff = (b < NB_PR) ? 0 : RN;       // union-space source offset
  for (int i = t; i < Sb; i += 512){
    int lo = 0;
    #pragma unroll
    for (int st = 256; st > 0; st >>= 1){
      int nx = lo + st;
      if (nx < 512 && off[nx] <= i) lo = nx;
    }
    unsigned int q = slab[(size_t)lo*ET + rblk[lo] + (i - off[lo])];
    atomicAdd(&lcnt[q >> 18], 1);
  }
  __syncthreads();
  int rv = lcnt[t];
  lsc[t] = rv;
  __syncthreads();
  for (int o = 1; o < 512; o <<= 1){
    int x = (t >= o) ? lsc[t-o] : 0;
    __syncthreads();
    lsc[t] += x;
    __syncthreads();
  }
  int start = lsc[t] - rv;
  lcur[t] = start;
  if (t < rows) rs[d0 + t] = s0b + start;
  __syncthreads();
  for (int i = t; i < Sb; i += 512){
    int lo = 0;
    #pragma unroll
    for (int st = 256; st > 0; st >>= 1){
      int nx = lo + st;
      if (nx < 512 && off[nx] <= i) lo = nx;
    }
    unsigned int q = slab[(size_t)lo*ET + rblk[lo] + (i - off[lo])];
    int r = (int)(q >> 18);
    int p = atomicAdd(&lcur[r], 1);
    col[s0b + p] = (int)(q & 0x3FFFFu) + srcoff;
  }
}

// ---- SpMM: one wave per dst row (union col / union gather base).
// BN=1: apply layer-1 BN+SiLU to each gathered element (side by union idx). ----
template<int BN>
__global__ __launch_bounds__(256) void spmm2_k(const int* __restrict__ rs, const int* __restrict__ col,
                                               const unsigned short* __restrict__ Xg,
                                               unsigned short* __restrict__ agg,
                                               const float* __restrict__ acU,
                                               const float* __restrict__ acI, int nrows){
  int w = (int)((blockIdx.x*256 + threadIdx.x) >> 6);
  int lane = threadIdx.x & 63;
  if (w >= nrows) return;
  int b = __builtin_amdgcn_readfirstlane(rs[w]);
  int e = __builtin_amdgcn_readfirstlane(rs[w+1]);
  float aU = 0, cU = 0, aI = 0, cI = 0;
  if (BN){ aU = acU[lane]; cU = acU[64+lane]; aI = acI[lane]; cI = acI[64+lane]; }
  float acc = 0.0f;
  for (int i = b; i < e; i += 8){
    int rem = e - i;                       // wave-uniform
    int idx0 = __builtin_nontemporal_load(&col[i]);
    int idx[8]; idx[0] = idx0;
    #pragma unroll
    for (int j = 1; j < 8; ++j)
      idx[j] = (j < rem) ? __builtin_nontemporal_load(&col[i + j]) : idx0;  // clamp tail
    float v[8];
    #pragma unroll
    for (int j = 0; j < 8; ++j){
      float x = bf2f(Xg[((size_t)(unsigned)idx[j] << 6) + lane]);
      if (BN){
        bool u = ((unsigned)idx[j] < RN);
        float a = u ? aU : aI, c = u ? cU : cI;
        float y = fmaf(a, x, c);
        x = y / (1.0f + expf(-y));
      }
      v[j] = x;
    }
    #pragma unroll
    for (int j = 0; j < 8; ++j)
      acc += (j < rem) ? v[j] : 0.0f;
  }
  int dg = e - b;
  float nrm = dg > 0 ? rsqrtf((float)dg) : 1.0f;
  __builtin_nontemporal_store(f2bf(acc * nrm), &agg[((size_t)w << 6) + lane]);
}

// ---- GEMM: H = silu?(Xd)@W[0:64] + Agg@W[64:128] + b, prepacked B frags,
//      fused BN sum/sumsq stats. BN=1 applies BN+SiLU to the dense operand. ----
template<int BN>
__global__ __launch_bounds__(256) void gemm2_k(const unsigned short* __restrict__ Agg,
                                               const unsigned short* __restrict__ Xd,
                                               const unsigned short* __restrict__ Wp,
                                               const float* __restrict__ bias,
                                               const float* __restrict__ ac,
                                               unsigned short* __restrict__ Hout,
                                               float* __restrict__ stats){
  __shared__ float ls[128];
  for (int t0 = threadIdx.x; t0 < 128; t0 += 256) ls[t0] = 0.0f;
  __syncthreads();
  int lane = threadIdx.x & 63;
  int gw = (int)((blockIdx.x*256 + threadIdx.x) >> 6);
  int nw = (int)(gridDim.x * 4);
  int c16 = lane & 15, kg = lane >> 4;

  short8v Bf[2][2][4];
  #pragma unroll
  for (int s = 0; s < 2; ++s)
    #pragma unroll
    for (int t2 = 0; t2 < 2; ++t2)
      #pragma unroll
      for (int c = 0; c < 4; ++c)
        Bf[s][t2][c] = ((const short8v*)Wp)[(((s*2 + t2)*4 + c)*4 + kg)*16 + c16];
  float bc[4];
  #pragma unroll
  for (int c = 0; c < 4; ++c) bc[c] = bias[c*16 + c16];
  float a0c[8], c0c[8], a1c[8], c1c[8];
  if (BN){
    #pragma unroll
    for (int j = 0; j < 8; ++j){
      a0c[j] = ac[kg*8 + j];      c0c[j] = ac[64 + kg*8 + j];
      a1c[j] = ac[32 + kg*8 + j]; c1c[j] = ac[96 + kg*8 + j];
    }
  }

  float ssum[4] = {0,0,0,0}, ssq[4] = {0,0,0,0};
  const int ntile = RN/16;
  for (int tile = gw; tile < ntile; tile += nw){
    int r0 = tile*16;
    int ar = r0 + c16;
    short8v A00 = ((const short8v*)Xd)[ar*8 + kg];
    short8v A01 = ((const short8v*)Xd)[ar*8 + 4 + kg];
    if (BN){
      #pragma unroll
      for (int j = 0; j < 8; ++j){
        float x = bf2f((unsigned short)A00[j]);
        float y = fmaf(a0c[j], x, c0c[j]);
        A00[j] = (short)f2bf(y / (1.0f + expf(-y)));
        float x1v = bf2f((unsigned short)A01[j]);
        float y1 = fmaf(a1c[j], x1v, c1c[j]);
        A01[j] = (short)f2bf(y1 / (1.0f + expf(-y1)));
      }
    }
    short8v A10 = ((const short8v*)Agg)[ar*8 + kg];
    short8v A11 = ((const short8v*)Agg)[ar*8 + 4 + kg];
    f32x4 acc4[4];
    #pragma unroll
    for (int c = 0; c < 4; ++c){ f32x4 z = {bc[c],bc[c],bc[c],bc[c]}; acc4[c] = z; }
    #pragma unroll
    for (int c = 0; c < 4; ++c){
      acc4[c] = __builtin_amdgcn_mfma_f32_16x16x32_bf16(A00, Bf[0][0][c], acc4[c], 0, 0, 0);
      acc4[c] = __builtin_amdgcn_mfma_f32_16x16x32_bf16(A01, Bf[0][1][c], acc4[c], 0, 0, 0);
      acc4[c] = __builtin_amdgcn_mfma_f32_16x16x32_bf16(A10, Bf[1][0][c], acc4[c], 0, 0, 0);
      acc4[c] = __builtin_amdgcn_mfma_f32_16x16x32_bf16(A11, Bf[1][1][c], acc4[c], 0, 0, 0);
    }
    int orow = r0 + kg*4;   // C layout: col = lane&15, row = (lane>>4)*4 + reg [m89]
    #pragma unroll
    for (int c = 0; c < 4; ++c)
      #pragma unroll
      for (int r = 0; r < 4; ++r){
        float v = acc4[c][r];
        ssum[c] += v; ssq[c] += v*v;
        __builtin_nontemporal_store(f2bf(v), &Hout[(size_t)(orow + r)*DIM + c*16 + c16]);
      }
  }
  #pragma unroll
  for (int c = 0; c < 4; ++c){
    atomicAdd(&ls[c*16 + c16], ssum[c]);
    atomicAdd(&ls[64 + c*16 + c16], ssq[c]);
  }
  __syncthreads();
  for (int t0 = threadIdx.x; t0 < 128; t0 += 256) atomicAdd(&stats[t0], ls[t0]);
}

// ---- BN finalize for both halves of a layer ----
__global__ __launch_bounds__(128) void bnfin2_k(const float* stats,
                                                const float* gI, const float* beI, float* acI,
                                                const float* gU, const float* beU, float* acU){
  int t = threadIdx.x, j = t & 63;
  const float* st = (t < 64) ? stats : stats + 128;
  float mu  = st[j]    * (1.0f/RN);
  float var = st[64+j] * (1.0f/RN) - mu*mu;
  float inv = rsqrtf(var + 1e-5f);
  if (t < 64){ float a = gI[j]*inv; acI[j] = a; acI[64+j] = beI[j] - mu*a; }
  else       { float a = gU[j]*inv; acU[j] = a; acU[64+j] = beU[j] - mu*a; }
}

// ---- BN + SiLU to d_out; user rows from Hu, item rows from Hi ----
__global__ __launch_bounds__(256) void bnout2_k(const unsigned short* __restrict__ Hu,
                                                const unsigned short* __restrict__ Hi,
                                                const float* __restrict__ acU,
                                                const float* __restrict__ acI,
                                                void* out, const int* __restrict__ flags, int n8){
  int i = blockIdx.x*256 + threadIdx.x;
  if (i >= n8) return;
  int item = (i >= RN*8);
  const float* ac = item ? acI : acU;
  us8 v = item ? ((const us8*)Hi)[i - RN*8] : ((const us8*)Hu)[i];
  int cb = (i*8) & 63;
  float o[8];
  #pragma unroll
  for (int r = 0; r < 8; ++r){
    float x = bf2f(v[r]);
    float y = ac[cb+r]*x + ac[64+cb+r];
    o[r] = y / (1.0f + expf(-y));
  }
  if (flags[0]){
    unsigned short* ob = (unsigned short*)out + (size_t)i*8;
    us8 wv;
    #pragma unroll
    for (int r = 0; r < 8; ++r) wv[r] = f2bf(o[r]);
    __builtin_nontemporal_store(wv, (us8*)ob);
  } else {
    float* ob = (float*)out + (size_t)i*8;
    f32x4 w0 = {o[0],o[1],o[2],o[3]}, w1 = {o[4],o[5],o[6],o[7]};
    __builtin_nontemporal_store(w0, (f32x4*)ob);
    __builtin_nontemporal_store(w1, (f32x4*)ob + 1);
  }
}

extern "C" void kernel_launch(void* const* d_in, const int* in_sizes, int n_in,
                              void* d_out, int out_size, void* d_ws, size_t ws_size,
                              hipStream_t stream){
  (void)in_sizes; (void)n_in; (void)out_size;
  const void* user_emb = d_in[0];
  const void* item_emb = d_in[1];
  const void* go_src   = d_in[18];
  const void* go_dst   = d_in[19];
  const void* back_src = d_in[20];
  const void* back_dst = d_in[21];

  char* ws = (char*)d_ws;
  size_t off = 0;
  auto alloc = [&](size_t bytes) -> void* {
    void* p = ws + off;
    off += (bytes + 255) & ~((size_t)255);
    return p;
  };
  int*   flags  = (int*)  alloc(64);
  float* params = (float*)alloc((size_t)49920*4);
  unsigned short* wpack = (unsigned short*)alloc((size_t)4*8192*2);
  float* bnac   = (float*)alloc(512*4);
  float* stats  = (float*)alloc(512*4);
  int*   Cmat   = (int*)  alloc((size_t)NBB*NBLKP*4);
  int*   Rloc   = (int*)  alloc((size_t)NBB*NBLKP*4);
  int*   Sbuf   = (int*)  alloc(1024*4);
  int*   s0g    = (int*)  alloc(1024*4);
  int*   rs_all = (int*)  alloc((size_t)(NR2+1)*4);
  int*   col_all= (int*)  alloc((size_t)2*NE*4);
  unsigned short* x1   = (unsigned short*)alloc((size_t)NR2*DIM*2);  // embeddings -> later agg2/h2u
  unsigned short* x2   = (unsigned short*)alloc((size_t)NR2*DIM*2);  // layer-1 raw output
  unsigned short* agg1 = (unsigned short*)alloc((size_t)RN*DIM*2);   // per-relation agg -> later h2i
  if (off > ws_size) return;  // visible as absmax == 5.8125

  unsigned int* slab = (unsigned int*)x2;   // 8MB alias; dead before gemmA writes x2u
  unsigned short* agg2 = x1;                // layer-2 union agg (x1 dead after gemmA)
  unsigned short* h2i  = agg1;              // layer-2 go output (items)
  unsigned short* h2u  = x1;                // layer-2 back output (users) over agg2's dead go half

  int* rs_go = rs_all;
  int* rs_bk = rs_all + RN;
  unsigned short* x1u = x1;
  unsigned short* x1i = x1 + (size_t)RN*DIM;
  unsigned short* x2u = x2;
  unsigned short* x2i = x2 + (size_t)RN*DIM;

  const int G8A = (NR2*DIM/8)/256;          // 12500
  const int GS1 = RN*64/256;                // 50000: one wave per row (per relation)
  const int GS2 = NR2*64/256;               // 100000: union layer-2 spmm

  float* b_go1 = params + 12288;
  float* b_bk1 = params + 24640;
  float* b_go2 = params + 36992;
  float* b_bk2 = params + 49344;
  float* g1u = params + 49408; float* be1u = params + 49472;
  float* g1i = params + 49536; float* be1i = params + 49600;
  float* g2u = params + 49664; float* be2u = params + 49728;
  float* g2i = params + 49792; float* be2i = params + 49856;

  detect_k<<<1,256,0,stream>>>((const unsigned short*)user_emb, (const unsigned int*)go_src, flags);
  zero_k<<<2,256,0,stream>>>((int*)stats, 512);
  Ptrs16 ps;
  for (int i = 0; i < 16; ++i) ps.p[i] = d_in[2+i];
  conv_params_k<<<196,256,0,stream>>>(ps, flags, params);
  prepack_k<<<128,256,0,stream>>>(params, wpack);
  conv_emb2_k<<<G8A,256,0,stream>>>(user_emb, item_emb, x1, flags, NR2*DIM/8);

  // ---- CSR build (block-local counting sort; validated R5; union col) ----
  pass1_k<<<NBLK,256,0,stream>>>((const unsigned int*)go_dst, (const unsigned int*)back_dst,
                                 Cmat, Rloc, flags);
  sizes_k<<<(NBB+3)/4,256,0,stream>>>(Cmat, Sbuf);
  scanS_k<<<1,1024,0,stream>>>(Sbuf, s0g, rs_all);
  pass2_k<<<NBLK,256,0,stream>>>((const unsigned int*)go_src, (const unsigned int*)go_dst,
                                 (const unsigned int*)back_src, (const unsigned int*)back_dst,
                                 Rloc, slab, flags);
  buildCSR2_k<<<NBB,512,0,stream>>>(Cmat, Rloc, s0g, slab, rs_all, col_all);

  // ---- layer 1 (per relation: spmm -> agg1, gemm -> x2 half + stats) ----
  spmm2_k<0><<<GS1,256,0,stream>>>(rs_go, col_all, x1, agg1, nullptr, nullptr, RN);
  gemm2_k<0><<<1024,256,0,stream>>>(agg1, x1i, wpack + 0*8192, b_go1, nullptr, x2i, stats + 0);
  spmm2_k<0><<<GS1,256,0,stream>>>(rs_bk, col_all, x1, agg1, nullptr, nullptr, RN);
  gemm2_k<0><<<1024,256,0,stream>>>(agg1, x1u, wpack + 1*8192, b_bk1, nullptr, x2u, stats + 128);
  bnfin2_k<<<1,128,0,stream>>>(stats + 0, g1i, be1i, bnac + 0, g1u, be1u, bnac + 128);

  // ---- layer 2: union spmm with fused BN+SiLU on gathered x2; gemms with
  //      fused BN+SiLU on the dense operand ----
  spmm2_k<1><<<GS2,256,0,stream>>>(rs_all, col_all, x2, agg2, bnac + 128, bnac + 0, NR2);
  gemm2_k<1><<<1024,256,0,stream>>>(agg2, x2i, wpack + 2*8192, b_go2, bnac + 0, h2i, stats + 256);
  gemm2_k<1><<<1024,256,0,stream>>>(agg2 + (size_t)RN*DIM, x2u, wpack + 3*8192, b_bk2,
                                    bnac + 128, h2u, stats + 384);
  bnfin2_k<<<1,128,0,stream>>>(stats + 256, g2i, be2i, bnac + 256, g2u, be2u, bnac + 384);
  bnout2_k<<<G8A,256,0,stream>>>(h2u, h2i, bnac + 384, bnac + 256, d_out, flags, NR2*DIM/8);
}

// Round 8
// 534.780 us; speedup vs baseline: 1.1366x; 1.0990x over previous
//
#include <hip/hip_runtime.h>
#include <cstdint>
#include <cstddef>

#define RN 200000   // nodes per side (NU == NI)
#define NR2 400000  // both sides
#define DIM 64
#define NE 1000000  // edges per relation
#define NB_PR 391   // buckets per relation (512 rows each)
#define NBB 782     // total buckets (go: 0..390, back: 391..781)
#define ET 4096     // edges per sort block
#define NBLK 489    // ceil(2*NE / ET)
#define NBLKP 512   // padded row length of C/Rloc (bucket-major)

typedef __attribute__((ext_vector_type(8))) short short8v;   // 8 x bf16 (4 VGPR)
typedef __attribute__((ext_vector_type(4))) float f32x4;
typedef __attribute__((ext_vector_type(8))) unsigned short us8;

struct Ptrs16 { const void* p[16]; };

__device__ __forceinline__ float bf2f(unsigned short u){
  unsigned int x = ((unsigned int)u) << 16;
  return __builtin_bit_cast(float, x);
}
__device__ __forceinline__ unsigned short f2bf(float f){
  unsigned int x = __builtin_bit_cast(unsigned int, f);
  unsigned int r = x + 0x7fffu + ((x >> 16) & 1u);   // RNE
  return (unsigned short)(r >> 16);
}

// ---- dtype sniffing ----
__global__ __launch_bounds__(256) void detect_k(const unsigned short* emb,
                                                const unsigned int* esrc,
                                                int* flags){
  __shared__ int cnt0, cnt1;
  int t = threadIdx.x;
  if (t == 0){ cnt0 = 0; cnt1 = 0; }
  __syncthreads();
  int c0 = 0, c1 = 0;
  #pragma unroll
  for (int s = 0; s < 4; ++s){
    int i = (t*4 + s) * 14;
    float af = fabsf(bf2f(emb[i]));
    if (af > 0.0009765625f && af < 32.0f) c0++;
    int e = t*4 + s;
    if (esrc[2*e + 1] != 0u) c1++;
  }
  atomicAdd(&cnt0, c0); atomicAdd(&cnt1, c1);
  __syncthreads();
  if (t == 0){
    flags[0] = (cnt0 > 512) ? 1 : 0;
    flags[1] = (cnt1 < 512) ? 1 : 0;
  }
}

__global__ __launch_bounds__(256) void zero_k(int* p, int n){
  int i = blockIdx.x*256 + threadIdx.x;
  if (i < n) p[i] = 0;
}

// ---- canonicalize the 16 small param arrays to fp32 ----
__global__ __launch_bounds__(256) void conv_params_k(Ptrs16 ps, const int* flags, float* out){
  const int offs[17] = {0,12288,12352,24640,24704,36992,37056,49344,49408,49472,
                        49536,49600,49664,49728,49792,49856,49920};
  int i = blockIdx.x*256 + threadIdx.x;
  if (i >= 49920) return;
  int a = 0;
  while (i >= offs[a+1]) ++a;
  int j = i - offs[a];
  float v = flags[0] ? bf2f(((const unsigned short*)ps.p[a])[j])
                     : ((const float*)ps.p[a])[j];
  out[i] = v;
}

// ---- prepack the 4 weight matrices into MFMA fragment order (bf16) ----
// Wp short index = frag_idx*8 + r, frag_idx = (((s*2+t2)*4+c)*4+kg)*16 + c16
__global__ __launch_bounds__(256) void prepack_k(const float* __restrict__ params,
                                                 unsigned short* __restrict__ wpack){
  int i = blockIdx.x*256 + threadIdx.x;
  if (i >= 4*8192) return;
  int m = i >> 13, f = i & 8191;
  const int woff[4] = {0, 12352, 24704, 37056};
  int r   = f & 7;
  int c16 = (f >> 3) & 15;
  int kg  = (f >> 7) & 3;
  int c   = (f >> 9) & 3;
  int t2  = (f >> 11) & 1;
  int s   = (f >> 12) & 1;
  int k = s*64 + t2*32 + kg*8 + r;
  wpack[i] = f2bf(params[woff[m] + k*DIM + c*16 + c16]);
}

// ---- canonicalize both embeddings into union bf16 buffer x1 (users, then items) ----
__global__ __launch_bounds__(256) void conv_emb2_k(const void* uin, const void* iin,
                                                   unsigned short* out,
                                                   const int* flags, int n8){
  int i = blockIdx.x*256 + threadIdx.x;
  if (i >= n8) return;
  int item = (i >= RN*8);
  const void* in = item ? iin : uin;
  int li = item ? i - RN*8 : i;
  us8 o;
  if (flags[0]){
    o = ((const us8*)in)[li];
  } else {
    const float* f = (const float*)in + (size_t)li*8;
    #pragma unroll
    for (int r = 0; r < 8; ++r) o[r] = f2bf(f[r]);
  }
  ((us8*)out)[i] = o;
}

// ==== CSR build: block-local counting sort (validated R5) ====
__global__ __launch_bounds__(256) void pass1_k(const unsigned int* go_dst,
                                               const unsigned int* back_dst,
                                               int* __restrict__ C, int* __restrict__ Rloc,
                                               const int* flags){
  __shared__ int h[1024];
  __shared__ int ps[256];
  int blk = blockIdx.x, t = threadIdx.x;
  #pragma unroll
  for (int q = 0; q < 4; ++q) h[t + q*256] = 0;
  __syncthreads();
  int i64 = flags[1];
  int e0 = blk*ET;
  #pragma unroll
  for (int j = 0; j < 16; ++j){
    int e = e0 + j*256 + t;
    if (e < 2*NE){
      int rel = e >= NE;
      int ei = rel ? e - NE : e;
      const unsigned int* pd = rel ? back_dst : go_dst;
      int d = i64 ? (int)pd[2*ei] : (int)pd[ei];
      int b = (rel ? NB_PR : 0) + (d >> 9);
      atomicAdd(&h[b], 1);
    }
  }
  __syncthreads();
  int c4[4], p4[4]; int s = 0;
  #pragma unroll
  for (int q = 0; q < 4; ++q){ c4[q] = h[t*4 + q]; p4[q] = s; s += c4[q]; }
  ps[t] = s;
  __syncthreads();
  for (int o = 1; o < 256; o <<= 1){
    int x = (t >= o) ? ps[t-o] : 0;
    __syncthreads();
    ps[t] += x;
    __syncthreads();
  }
  int base = (t > 0) ? ps[t-1] : 0;
  #pragma unroll
  for (int q = 0; q < 4; ++q){
    int b = t*4 + q;
    if (b < NBB){
      C[b*NBLKP + blk]    = c4[q];
      Rloc[b*NBLKP + blk] = base + p4[q];
    }
  }
}

__global__ __launch_bounds__(256) void sizes_k(const int* __restrict__ C, int* __restrict__ S){
  int w = blockIdx.x*4 + (threadIdx.x >> 6);
  int lane = threadIdx.x & 63;
  if (w >= NBB) return;
  int sum = 0;
  for (int k = lane; k < NBLK; k += 64) sum += C[w*NBLKP + k];
  #pragma unroll
  for (int o = 32; o > 0; o >>= 1) sum += __shfl_down(sum, o, 64);
  if (lane == 0) S[w] = sum;
}

__global__ __launch_bounds__(1024) void scanS_k(const int* __restrict__ S, int* __restrict__ s0,
                                                int* __restrict__ rs){
  __shared__ int sh[1024];
  int t = threadIdx.x;
  int v = (t < NBB) ? S[t] : 0;
  sh[t] = v;
  __syncthreads();
  for (int o = 1; o < 1024; o <<= 1){
    int x = (t >= o) ? sh[t-o] : 0;
    __syncthreads();
    sh[t] += x;
    __syncthreads();
  }
  if (t < NBB) s0[t] = sh[t] - v;
  if (t == NBB-1){ s0[NBB] = sh[t]; rs[NR2] = 2*NE; }
}

__global__ __launch_bounds__(256) void pass2_k(const unsigned int* go_src, const unsigned int* go_dst,
                                               const unsigned int* back_src, const unsigned int* back_dst,
                                               const int* __restrict__ Rloc,
                                               unsigned int* __restrict__ slab, const int* flags){
  __shared__ int lcur[1024];
  int blk = blockIdx.x, t = threadIdx.x;
  for (int b = t; b < NBB; b += 256) lcur[b] = Rloc[b*NBLKP + blk];
  __syncthreads();
  int i64 = flags[1];
  int e0 = blk*ET;
  #pragma unroll
  for (int j = 0; j < 16; ++j){
    int e = e0 + j*256 + t;
    if (e < 2*NE){
      int rel = e >= NE;
      int ei = rel ? e - NE : e;
      const unsigned int* pd = rel ? back_dst : go_dst;
      const unsigned int* psr = rel ? back_src : go_src;
      int d  = i64 ? (int)pd[2*ei]  : (int)pd[ei];
      int sc = i64 ? (int)psr[2*ei] : (int)psr[ei];
      int b = (rel ? NB_PR : 0) + (d >> 9);
      int r = d & 511;
      int pos = atomicAdd(&lcur[b], 1);
      slab[(size_t)blk*ET + pos] = (unsigned)sc | ((unsigned)r << 18);
    }
  }
}

// col written in UNION space (+RN for back-relation sources = items)
__global__ __launch_bounds__(512) void buildCSR2_k(const int* __restrict__ C,
                                                   const int* __restrict__ Rloc,
                                                   const int* __restrict__ s0g,
                                                   const unsigned int* __restrict__ slab,
                                                   int* __restrict__ rs, int* __restrict__ col){
  __shared__ int cblk[NBLKP], rblk[NBLKP], off[NBLKP];
  __shared__ int lcnt[512], lsc[512], lcur[512];
  int b = blockIdx.x, t = threadIdx.x;
  cblk[t] = (t < NBLK) ? C[b*NBLKP + t] : 0;
  rblk[t] = (t < NBLK) ? Rloc[b*NBLKP + t] : 0;
  lcnt[t] = 0;
  int v = cblk[t];
  off[t] = v;
  __syncthreads();
  for (int o = 1; o < 512; o <<= 1){
    int x = (t >= o) ? off[t-o] : 0;
    __syncthreads();
    off[t] += x;
    __syncthreads();
  }
  int Sb = off[511];
  int excl = off[t] - v;
  __syncthreads();
  off[t] = excl;
  __syncthreads();
  int s0b = s0g[b];
  int d0 = (b < NB_PR) ? b*512 : RN + (b - NB_PR)*512;
  int relEnd = (b < NB_PR) ? RN : NR2;
  int rows = relEnd - d0; if (rows > 512) rows = 512;
  int srcoff = (b < NB_PR) ? 0 : RN;       // union-space source offset
  for (int i = t; i < Sb; i += 512){
    int lo = 0;
    #pragma unroll
    for (int st = 256; st > 0; st >>= 1){
      int nx = lo + st;
      if (nx < 512 && off[nx] <= i) lo = nx;
    }
    unsigned int q = slab[(size_t)lo*ET + rblk[lo] + (i - off[lo])];
    atomicAdd(&lcnt[q >> 18], 1);
  }
  __syncthreads();
  int rv = lcnt[t];
  lsc[t] = rv;
  __syncthreads();
  for (int o = 1; o < 512; o <<= 1){
    int x = (t >= o) ? lsc[t-o] : 0;
    __syncthreads();
    lsc[t] += x;
    __syncthreads();
  }
  int start = lsc[t] - rv;
  lcur[t] = start;
  if (t < rows) rs[d0 + t] = s0b + start;
  __syncthreads();
  for (int i = t; i < Sb; i += 512){
    int lo = 0;
    #pragma unroll
    for (int st = 256; st > 0; st >>= 1){
      int nx = lo + st;
      if (nx < 512 && off[nx] <= i) lo = nx;
    }
    unsigned int q = slab[(size_t)lo*ET + rblk[lo] + (i - off[lo])];
    int r = (int)(q >> 18);
    int p = atomicAdd(&lcur[r], 1);
    col[s0b + p] = (int)(q & 0x3FFFFu) + srcoff;
  }
}

// ---- SpMM: one wave per dst row; 16 gathers in flight (R8 MLP deepening).
// Tail clamps to idx0 BEFORE the gather -> dups hit L1; uniform predicate acc. ----
__global__ __launch_bounds__(256) void spmm2_k(const int* __restrict__ rs, const int* __restrict__ col,
                                               const unsigned short* __restrict__ Xg,
                                               unsigned short* __restrict__ agg, int nrows){
  int w = (int)((blockIdx.x*256 + threadIdx.x) >> 6);
  int lane = threadIdx.x & 63;
  if (w >= nrows) return;
  int b = __builtin_amdgcn_readfirstlane(rs[w]);
  int e = __builtin_amdgcn_readfirstlane(rs[w+1]);
  float acc = 0.0f;
  for (int i = b; i < e; i += 16){
    int rem = e - i;                       // wave-uniform
    int idx0 = col[i];
    int idx[16]; idx[0] = idx0;
    #pragma unroll
    for (int j = 1; j < 16; ++j)
      idx[j] = (j < rem) ? col[i + j] : idx0;   // clamp tail to a valid row
    float v[16];
    #pragma unroll
    for (int j = 0; j < 16; ++j)
      v[j] = bf2f(Xg[((size_t)(unsigned)idx[j] << 6) + lane]);
    #pragma unroll
    for (int j = 0; j < 16; ++j)
      acc += (j < rem) ? v[j] : 0.0f;
  }
  int dg = e - b;
  float nrm = dg > 0 ? rsqrtf((float)dg) : 1.0f;
  __builtin_nontemporal_store(f2bf(acc * nrm), &agg[((size_t)w << 6) + lane]);
}

// ---- GEMM: H = Xd@W[0:64] + Agg@W[64:128] + b, prepacked B frags, fused BN stats ----
__global__ __launch_bounds__(256) void gemm2_k(const unsigned short* __restrict__ Agg,
                                               const unsigned short* __restrict__ Xd,
                                               const unsigned short* __restrict__ Wp,
                                               const float* __restrict__ bias,
                                               unsigned short* __restrict__ Hout,
                                               float* __restrict__ stats){
  __shared__ float ls[128];
  for (int t0 = threadIdx.x; t0 < 128; t0 += 256) ls[t0] = 0.0f;
  __syncthreads();
  int lane = threadIdx.x & 63;
  int gw = (int)((blockIdx.x*256 + threadIdx.x) >> 6);
  int nw = (int)(gridDim.x * 4);
  int c16 = lane & 15, kg = lane >> 4;

  short8v Bf[2][2][4];
  #pragma unroll
  for (int s = 0; s < 2; ++s)
    #pragma unroll
    for (int t2 = 0; t2 < 2; ++t2)
      #pragma unroll
      for (int c = 0; c < 4; ++c)
        Bf[s][t2][c] = ((const short8v*)Wp)[(((s*2 + t2)*4 + c)*4 + kg)*16 + c16];
  float bc[4];
  #pragma unroll
  for (int c = 0; c < 4; ++c) bc[c] = bias[c*16 + c16];

  float ssum[4] = {0,0,0,0}, ssq[4] = {0,0,0,0};
  const int ntile = RN/16;
  for (int tile = gw; tile < ntile; tile += nw){
    int r0 = tile*16;
    int ar = r0 + c16;
    short8v A00 = ((const short8v*)Xd)[ar*8 + kg];
    short8v A01 = ((const short8v*)Xd)[ar*8 + 4 + kg];
    short8v A10 = ((const short8v*)Agg)[ar*8 + kg];
    short8v A11 = ((const short8v*)Agg)[ar*8 + 4 + kg];
    f32x4 acc4[4];
    #pragma unroll
    for (int c = 0; c < 4; ++c){ f32x4 z = {bc[c],bc[c],bc[c],bc[c]}; acc4[c] = z; }
    #pragma unroll
    for (int c = 0; c < 4; ++c){
      acc4[c] = __builtin_amdgcn_mfma_f32_16x16x32_bf16(A00, Bf[0][0][c], acc4[c], 0, 0, 0);
      acc4[c] = __builtin_amdgcn_mfma_f32_16x16x32_bf16(A01, Bf[0][1][c], acc4[c], 0, 0, 0);
      acc4[c] = __builtin_amdgcn_mfma_f32_16x16x32_bf16(A10, Bf[1][0][c], acc4[c], 0, 0, 0);
      acc4[c] = __builtin_amdgcn_mfma_f32_16x16x32_bf16(A11, Bf[1][1][c], acc4[c], 0, 0, 0);
    }
    int orow = r0 + kg*4;   // C layout: col = lane&15, row = (lane>>4)*4 + reg [m89]
    #pragma unroll
    for (int c = 0; c < 4; ++c)
      #pragma unroll
      for (int r = 0; r < 4; ++r){
        float v = acc4[c][r];
        ssum[c] += v; ssq[c] += v*v;
        __builtin_nontemporal_store(f2bf(v), &Hout[(size_t)(orow + r)*DIM + c*16 + c16]);
      }
  }
  #pragma unroll
  for (int c = 0; c < 4; ++c){
    atomicAdd(&ls[c*16 + c16], ssum[c]);
    atomicAdd(&ls[64 + c*16 + c16], ssq[c]);
  }
  __syncthreads();
  for (int t0 = threadIdx.x; t0 < 128; t0 += 256) atomicAdd(&stats[t0], ls[t0]);
}

// ---- BN finalize for both halves of a layer ----
__global__ __launch_bounds__(128) void bnfin2_k(const float* stats,
                                                const float* gI, const float* beI, float* acI,
                                                const float* gU, const float* beU, float* acU){
  int t = threadIdx.x, j = t & 63;
  const float* st = (t < 64) ? stats : stats + 128;
  float mu  = st[j]    * (1.0f/RN);
  float var = st[64+j] * (1.0f/RN) - mu*mu;
  float inv = rsqrtf(var + 1e-5f);
  if (t < 64){ float a = gI[j]*inv; acI[j] = a; acI[64+j] = beI[j] - mu*a; }
  else       { float a = gU[j]*inv; acU[j] = a; acU[64+j] = beU[j] - mu*a; }
}

// ---- BN + SiLU in-place over the union buffer (users half then items half) ----
__global__ __launch_bounds__(256) void bnapply2_k(unsigned short* H,
                                                  const float* __restrict__ acU,
                                                  const float* __restrict__ acI, int n8){
  int i = blockIdx.x*256 + threadIdx.x;
  if (i >= n8) return;
  const float* ac = (i < RN*8) ? acU : acI;
  us8 v = ((us8*)H)[i];
  int cb = (i*8) & 63;
  #pragma unroll
  for (int r = 0; r < 8; ++r){
    float x = bf2f(v[r]);
    float y = ac[cb+r]*x + ac[64+cb+r];
    float o = y / (1.0f + expf(-y));
    v[r] = f2bf(o);
  }
  ((us8*)H)[i] = v;
}

// ---- BN + SiLU to d_out; user rows from Hu, item rows from Hi ----
__global__ __launch_bounds__(256) void bnout2_k(const unsigned short* __restrict__ Hu,
                                                const unsigned short* __restrict__ Hi,
                                                const float* __restrict__ acU,
                                                const float* __restrict__ acI,
                                                void* out, const int* __restrict__ flags, int n8){
  int i = blockIdx.x*256 + threadIdx.x;
  if (i >= n8) return;
  int item = (i >= RN*8);
  const float* ac = item ? acI : acU;
  us8 v = item ? ((const us8*)Hi)[i - RN*8] : ((const us8*)Hu)[i];
  int cb = (i*8) & 63;
  float o[8];
  #pragma unroll
  for (int r = 0; r < 8; ++r){
    float x = bf2f(v[r]);
    float y = ac[cb+r]*x + ac[64+cb+r];
    o[r] = y / (1.0f + expf(-y));
  }
  if (flags[0]){
    unsigned short* ob = (unsigned short*)out + (size_t)i*8;
    us8 wv;
    #pragma unroll
    for (int r = 0; r < 8; ++r) wv[r] = f2bf(o[r]);
    __builtin_nontemporal_store(wv, (us8*)ob);
  } else {
    float* ob = (float*)out + (size_t)i*8;
    f32x4 w0 = {o[0],o[1],o[2],o[3]}, w1 = {o[4],o[5],o[6],o[7]};
    __builtin_nontemporal_store(w0, (f32x4*)ob);
    __builtin_nontemporal_store(w1, (f32x4*)ob + 1);
  }
}

extern "C" void kernel_launch(void* const* d_in, const int* in_sizes, int n_in,
                              void* d_out, int out_size, void* d_ws, size_t ws_size,
                              hipStream_t stream){
  (void)in_sizes; (void)n_in; (void)out_size;
  const void* user_emb = d_in[0];
  const void* item_emb = d_in[1];
  const void* go_src   = d_in[18];
  const void* go_dst   = d_in[19];
  const void* back_src = d_in[20];
  const void* back_dst = d_in[21];

  char* ws = (char*)d_ws;
  size_t off = 0;
  auto alloc = [&](size_t bytes) -> void* {
    void* p = ws + off;
    off += (bytes + 255) & ~((size_t)255);
    return p;
  };
  int*   flags  = (int*)  alloc(64);
  float* params = (float*)alloc((size_t)49920*4);
  unsigned short* wpack = (unsigned short*)alloc((size_t)4*8192*2);
  float* bnac   = (float*)alloc(512*4);
  float* stats  = (float*)alloc(512*4);
  int*   Cmat   = (int*)  alloc((size_t)NBB*NBLKP*4);
  int*   Rloc   = (int*)  alloc((size_t)NBB*NBLKP*4);
  int*   Sbuf   = (int*)  alloc(1024*4);
  int*   s0g    = (int*)  alloc(1024*4);
  int*   rs_all = (int*)  alloc((size_t)(NR2+1)*4);
  int*   col_all= (int*)  alloc((size_t)2*NE*4);
  unsigned short* x1   = (unsigned short*)alloc((size_t)NR2*DIM*2);  // embeddings -> later agg2/h2u
  unsigned short* x2   = (unsigned short*)alloc((size_t)NR2*DIM*2);  // layer-1 output (silu'd in place)
  unsigned short* agg1 = (unsigned short*)alloc((size_t)RN*DIM*2);   // per-relation agg -> later h2i
  if (off > ws_size) return;  // visible as absmax == 5.8125

  unsigned int* slab = (unsigned int*)x2;   // 8MB alias; dead before gemm writes x2
  unsigned short* agg2 = x1;                // layer-2 agg (x1 dead after layer-1 gemms)
  unsigned short* h2i  = agg1;              // layer-2 go output (items)
  unsigned short* h2u  = x1;                // layer-2 back output (users) over agg2's dead go half

  int* rs_go = rs_all;
  int* rs_bk = rs_all + RN;
  unsigned short* x1u = x1;
  unsigned short* x1i = x1 + (size_t)RN*DIM;
  unsigned short* x2u = x2;
  unsigned short* x2i = x2 + (size_t)RN*DIM;

  const int G8A = (NR2*DIM/8)/256;          // 12500
  const int GS1 = RN*64/256;                // 50000: one wave per row (per relation)

  float* b_go1 = params + 12288;
  float* b_bk1 = params + 24640;
  float* b_go2 = params + 36992;
  float* b_bk2 = params + 49344;
  float* g1u = params + 49408; float* be1u = params + 49472;
  float* g1i = params + 49536; float* be1i = params + 49600;
  float* g2u = params + 49664; float* be2u = params + 49728;
  float* g2i = params + 49792; float* be2i = params + 49856;

  detect_k<<<1,256,0,stream>>>((const unsigned short*)user_emb, (const unsigned int*)go_src, flags);
  zero_k<<<2,256,0,stream>>>((int*)stats, 512);
  Ptrs16 ps;
  for (int i = 0; i < 16; ++i) ps.p[i] = d_in[2+i];
  conv_params_k<<<196,256,0,stream>>>(ps, flags, params);
  prepack_k<<<128,256,0,stream>>>(params, wpack);
  conv_emb2_k<<<G8A,256,0,stream>>>(user_emb, item_emb, x1, flags, NR2*DIM/8);

  // ---- CSR build (block-local counting sort; validated R5; union col) ----
  pass1_k<<<NBLK,256,0,stream>>>((const unsigned int*)go_dst, (const unsigned int*)back_dst,
                                 Cmat, Rloc, flags);
  sizes_k<<<(NBB+3)/4,256,0,stream>>>(Cmat, Sbuf);
  scanS_k<<<1,1024,0,stream>>>(Sbuf, s0g, rs_all);
  pass2_k<<<NBLK,256,0,stream>>>((const unsigned int*)go_src, (const unsigned int*)go_dst,
                                 (const unsigned int*)back_src, (const unsigned int*)back_dst,
                                 Rloc, slab, flags);
  buildCSR2_k<<<NBB,512,0,stream>>>(Cmat, Rloc, s0g, slab, rs_all, col_all);

  // ---- layer 1 (per relation: spmm -> agg1, gemm -> x2 half + stats) ----
  spmm2_k<<<GS1,256,0,stream>>>(rs_go, col_all, x1, agg1, RN);
  gemm2_k<<<1024,256,0,stream>>>(agg1, x1i, wpack + 0*8192, b_go1, x2i, stats + 0);
  spmm2_k<<<GS1,256,0,stream>>>(rs_bk, col_all, x1, agg1, RN);
  gemm2_k<<<1024,256,0,stream>>>(agg1, x1u, wpack + 1*8192, b_bk1, x2u, stats + 128);
  bnfin2_k<<<1,128,0,stream>>>(stats + 0, g1i, be1i, bnac + 0, g1u, be1u, bnac + 128);

  // ---- layer 2: materialize silu(x2), two per-relation spmms (25.6MB working
  //      set each -> L2-friendly), gemms read silu'd x2 directly ----
  bnapply2_k<<<G8A,256,0,stream>>>(x2, bnac + 128, bnac + 0, NR2*DIM/8);
  spmm2_k<<<GS1,256,0,stream>>>(rs_go, col_all, x2, agg2, RN);
  spmm2_k<<<GS1,256,0,stream>>>(rs_bk, col_all, x2, agg2 + (size_t)RN*DIM, RN);
  gemm2_k<<<1024,256,0,stream>>>(agg2, x2i, wpack + 2*8192, b_go2, h2i, stats + 256);
  gemm2_k<<<1024,256,0,stream>>>(agg2 + (size_t)RN*DIM, x2u, wpack + 3*8192, b_bk2, h2u, stats + 384);
  bnfin2_k<<<1,128,0,stream>>>(stats + 256, g2i, be2i, bnac + 256, g2u, be2u, bnac + 384);
  bnout2_k<<<G8A,256,0,stream>>>(h2u, h2i, bnac + 384, bnac + 256, d_out, flags, NR2*DIM/8);
}

// Round 9
// 503.788 us; speedup vs baseline: 1.2065x; 1.0615x over previous
//
#include <hip/hip_runtime.h>
#include <cstdint>
#include <cstddef>

#define RN 200000   // nodes per side (NU == NI)
#define NR2 400000  // both sides
#define DIM 64
#define NE 1000000  // edges per relation
#define NB_PR 391   // buckets per relation (512 rows each)
#define NBB 782     // total buckets (go: 0..390, back: 391..781)
#define ET 4096     // edges per sort block
#define NBLK 489    // ceil(2*NE / ET)
#define NBLKP 512   // padded row length of C/Rloc (bucket-major)

typedef __attribute__((ext_vector_type(8))) short short8v;   // 8 x bf16 (4 VGPR)
typedef __attribute__((ext_vector_type(4))) float f32x4;
typedef __attribute__((ext_vector_type(8))) unsigned short us8;

struct Ptrs16 { const void* p[16]; };

__device__ __forceinline__ float bf2f(unsigned short u){
  unsigned int x = ((unsigned int)u) << 16;
  return __builtin_bit_cast(float, x);
}
__device__ __forceinline__ unsigned short f2bf(float f){
  unsigned int x = __builtin_bit_cast(unsigned int, f);
  unsigned int r = x + 0x7fffu + ((x >> 16) & 1u);   // RNE
  return (unsigned short)(r >> 16);
}

// ---- dtype sniff + small-param convert + stats zero (single block) ----
__global__ __launch_bounds__(256) void detect2_k(const unsigned short* emb,
                                                 const unsigned int* esrc,
                                                 int* flags, Ptrs16 ps,
                                                 float* params, float* stats){
  __shared__ int cnt0, cnt1, sf0;
  int t = threadIdx.x;
  if (t == 0){ cnt0 = 0; cnt1 = 0; }
  __syncthreads();
  int c0 = 0, c1 = 0;
  #pragma unroll
  for (int s = 0; s < 4; ++s){
    int i = (t*4 + s) * 14;
    float af = fabsf(bf2f(emb[i]));
    if (af > 0.0009765625f && af < 32.0f) c0++;
    int e = t*4 + s;
    if (esrc[2*e + 1] != 0u) c1++;
  }
  atomicAdd(&cnt0, c0); atomicAdd(&cnt1, c1);
  __syncthreads();
  if (t == 0){
    int f0 = (cnt0 > 512) ? 1 : 0;
    int f1 = (cnt1 < 512) ? 1 : 0;
    flags[0] = f0; flags[1] = f1; sf0 = f0;
  }
  __syncthreads();
  int f0 = sf0;
  const int aidx[12] = {1,3,5,7,8,9,10,11,12,13,14,15};
  const int aoff[12] = {12288,24640,36992,49344,49408,49472,49536,49600,49664,49728,49792,49856};
  for (int base = t; base < 768; base += 256){
    int a = base >> 6, j = base & 63;
    const void* p = ps.p[aidx[a]];
    params[aoff[a] + j] = f0 ? bf2f(((const unsigned short*)p)[j]) : ((const float*)p)[j];
  }
  for (int z = t; z < 512; z += 256) stats[z] = 0.0f;
}

// ---- prepack the 4 weight matrices (raw inputs) into MFMA fragment order ----
__global__ __launch_bounds__(256) void prepack_k(Ptrs16 ps, const int* flags,
                                                 unsigned short* __restrict__ wpack){
  int i = blockIdx.x*256 + threadIdx.x;
  if (i >= 4*8192) return;
  int m = i >> 13, f = i & 8191;
  int r   = f & 7;
  int c16 = (f >> 3) & 15;
  int kg  = (f >> 7) & 3;
  int c   = (f >> 9) & 3;
  int t2  = (f >> 11) & 1;
  int s   = (f >> 12) & 1;
  int k = s*64 + t2*32 + kg*8 + r;
  int j = k*DIM + c*16 + c16;
  const void* wp = ps.p[m*2];          // W_go1, W_back1, W_go2, W_back2
  float v = flags[0] ? bf2f(((const unsigned short*)wp)[j]) : ((const float*)wp)[j];
  wpack[i] = f2bf(v);
}

// ---- canonicalize both embeddings into union bf16 buffer x1 (users, then items) ----
__global__ __launch_bounds__(256) void conv_emb2_k(const void* uin, const void* iin,
                                                   unsigned short* out,
                                                   const int* flags, int n8){
  int i = blockIdx.x*256 + threadIdx.x;
  if (i >= n8) return;
  int item = (i >= RN*8);
  const void* in = item ? iin : uin;
  int li = item ? i - RN*8 : i;
  us8 o;
  if (flags[0]){
    o = ((const us8*)in)[li];
  } else {
    const float* f = (const float*)in + (size_t)li*8;
    #pragma unroll
    for (int r = 0; r < 8; ++r) o[r] = f2bf(f[r]);
  }
  ((us8*)out)[i] = o;
}

// ==== CSR build: block-local counting sort (validated R5) ====
__global__ __launch_bounds__(256) void pass1_k(const unsigned int* go_dst,
                                               const unsigned int* back_dst,
                                               int* __restrict__ C, int* __restrict__ Rloc,
                                               const int* flags){
  __shared__ int h[1024];
  __shared__ int ps[256];
  int blk = blockIdx.x, t = threadIdx.x;
  #pragma unroll
  for (int q = 0; q < 4; ++q) h[t + q*256] = 0;
  __syncthreads();
  int i64 = flags[1];
  int e0 = blk*ET;
  #pragma unroll
  for (int j = 0; j < 16; ++j){
    int e = e0 + j*256 + t;
    if (e < 2*NE){
      int rel = e >= NE;
      int ei = rel ? e - NE : e;
      const unsigned int* pd = rel ? back_dst : go_dst;
      int d = i64 ? (int)pd[2*ei] : (int)pd[ei];
      int b = (rel ? NB_PR : 0) + (d >> 9);
      atomicAdd(&h[b], 1);
    }
  }
  __syncthreads();
  int c4[4], p4[4]; int s = 0;
  #pragma unroll
  for (int q = 0; q < 4; ++q){ c4[q] = h[t*4 + q]; p4[q] = s; s += c4[q]; }
  ps[t] = s;
  __syncthreads();
  for (int o = 1; o < 256; o <<= 1){
    int x = (t >= o) ? ps[t-o] : 0;
    __syncthreads();
    ps[t] += x;
    __syncthreads();
  }
  int base = (t > 0) ? ps[t-1] : 0;
  #pragma unroll
  for (int q = 0; q < 4; ++q){
    int b = t*4 + q;
    if (b < NBB){
      C[b*NBLKP + blk]    = c4[q];
      Rloc[b*NBLKP + blk] = base + p4[q];
    }
  }
}

__global__ __launch_bounds__(256) void sizes_k(const int* __restrict__ C, int* __restrict__ S){
  int w = blockIdx.x*4 + (threadIdx.x >> 6);
  int lane = threadIdx.x & 63;
  if (w >= NBB) return;
  int sum = 0;
  for (int k = lane; k < NBLK; k += 64) sum += C[w*NBLKP + k];
  #pragma unroll
  for (int o = 32; o > 0; o >>= 1) sum += __shfl_down(sum, o, 64);
  if (lane == 0) S[w] = sum;
}

__global__ __launch_bounds__(1024) void scanS_k(const int* __restrict__ S, int* __restrict__ s0,
                                                int* __restrict__ rs){
  __shared__ int sh[1024];
  int t = threadIdx.x;
  int v = (t < NBB) ? S[t] : 0;
  sh[t] = v;
  __syncthreads();
  for (int o = 1; o < 1024; o <<= 1){
    int x = (t >= o) ? sh[t-o] : 0;
    __syncthreads();
    sh[t] += x;
    __syncthreads();
  }
  if (t < NBB) s0[t] = sh[t] - v;
  if (t == NBB-1){ s0[NBB] = sh[t]; rs[NR2] = 2*NE; }
}

__global__ __launch_bounds__(256) void pass2_k(const unsigned int* go_src, const unsigned int* go_dst,
                                               const unsigned int* back_src, const unsigned int* back_dst,
                                               const int* __restrict__ Rloc,
                                               unsigned int* __restrict__ slab, const int* flags){
  __shared__ int lcur[1024];
  int blk = blockIdx.x, t = threadIdx.x;
  for (int b = t; b < NBB; b += 256) lcur[b] = Rloc[b*NBLKP + blk];
  __syncthreads();
  int i64 = flags[1];
  int e0 = blk*ET;
  #pragma unroll
  for (int j = 0; j < 16; ++j){
    int e = e0 + j*256 + t;
    if (e < 2*NE){
      int rel = e >= NE;
      int ei = rel ? e - NE : e;
      const unsigned int* pd = rel ? back_dst : go_dst;
      const unsigned int* psr = rel ? back_src : go_src;
      int d  = i64 ? (int)pd[2*ei]  : (int)pd[ei];
      int sc = i64 ? (int)psr[2*ei] : (int)psr[ei];
      int b = (rel ? NB_PR : 0) + (d >> 9);
      int r = d & 511;
      int pos = atomicAdd(&lcur[b], 1);
      slab[(size_t)blk*ET + pos] = (unsigned)sc | ((unsigned)r << 18);
    }
  }
}

// col written in UNION space (+RN for back-relation sources = items)
__global__ __launch_bounds__(512) void buildCSR2_k(const int* __restrict__ C,
                                                   const int* __restrict__ Rloc,
                                                   const int* __restrict__ s0g,
                                                   const unsigned int* __restrict__ slab,
                                                   int* __restrict__ rs, int* __restrict__ col){
  __shared__ int cblk[NBLKP], rblk[NBLKP], off[NBLKP];
  __shared__ int lcnt[512], lsc[512], lcur[512];
  int b = blockIdx.x, t = threadIdx.x;
  cblk[t] = (t < NBLK) ? C[b*NBLKP + t] : 0;
  rblk[t] = (t < NBLK) ? Rloc[b*NBLKP + t] : 0;
  lcnt[t] = 0;
  int v = cblk[t];
  off[t] = v;
  __syncthreads();
  for (int o = 1; o < 512; o <<= 1){
    int x = (t >= o) ? off[t-o] : 0;
    __syncthreads();
    off[t] += x;
    __syncthreads();
  }
  int Sb = off[511];
  int excl = off[t] - v;
  __syncthreads();
  off[t] = excl;
  __syncthreads();
  int s0b = s0g[b];
  int d0 = (b < NB_PR) ? b*512 : RN + (b - NB_PR)*512;
  int relEnd = (b < NB_PR) ? RN : NR2;
  int rows = relEnd - d0; if (rows > 512) rows = 512;
  int srcoff = (b < NB_PR) ? 0 : RN;       // union-space source offset
  for (int i = t; i < Sb; i += 512){
    int lo = 0;
    #pragma unroll
    for (int st = 256; st > 0; st >>= 1){
      int nx = lo + st;
      if (nx < 512 && off[nx] <= i) lo = nx;
    }
    unsigned int q = slab[(size_t)lo*ET + rblk[lo] + (i - off[lo])];
    atomicAdd(&lcnt[q >> 18], 1);
  }
  __syncthreads();
  int rv = lcnt[t];
  lsc[t] = rv;
  __syncthreads();
  for (int o = 1; o < 512; o <<= 1){
    int x = (t >= o) ? lsc[t-o] : 0;
    __syncthreads();
    lsc[t] += x;
    __syncthreads();
  }
  int start = lsc[t] - rv;
  lcur[t] = start;
  if (t < rows) rs[d0 + t] = s0b + start;
  __syncthreads();
  for (int i = t; i < Sb; i += 512){
    int lo = 0;
    #pragma unroll
    for (int st = 256; st > 0; st >>= 1){
      int nx = lo + st;
      if (nx < 512 && off[nx] <= i) lo = nx;
    }
    unsigned int q = slab[(size_t)lo*ET + rblk[lo] + (i - off[lo])];
    int r = (int)(q >> 18);
    int p = atomicAdd(&lcur[r], 1);
    col[s0b + p] = (int)(q & 0x3FFFFu) + srcoff;
  }
}

// ---- SpMM R9: HALF-WAVE per dst row. Each of 32 lanes loads a uint (2 bf16
// cols); 16-deep batches -> 16 insts x 256 B = 4 KB/wave in flight (2x R8).
// Tail slots clamp to edge 0 (L1 hits); gathered idx clamped to [0,NR2). ----
__global__ __launch_bounds__(256) void spmm3_k(const int* __restrict__ rs, const int* __restrict__ col,
                                               const unsigned short* __restrict__ Xg,
                                               unsigned short* __restrict__ agg, int nrows){
  int wv = (int)((blockIdx.x*256 + threadIdx.x) >> 6);
  int lane = threadIdx.x & 63;
  int half = lane >> 5, hl = lane & 31;
  int row = wv*2 + half;               // grid exact (nrows even)
  if (row >= nrows) return;
  int b = rs[row], e = rs[row+1];      // uniform within half-wave
  int deg = e - b;
  int md = max(__shfl(deg, 0), __shfl(deg, 32));   // wave-uniform trip bound
  float ax = 0.0f, ay = 0.0f;
  for (int i = 0; i < md; i += 16){
    int idx[16];
    #pragma unroll
    for (int j = 0; j < 16; ++j){
      int o = i + j;
      int cid = b + ((o < deg) ? o : 0);
      int ix = col[cid];
      idx[j] = ((unsigned)ix < (unsigned)NR2) ? ix : 0;   // safety clamp
    }
    unsigned int v[16];
    #pragma unroll
    for (int j = 0; j < 16; ++j)
      v[j] = *(const unsigned int*)((const char*)Xg + (((size_t)(unsigned)idx[j]) << 7) + (hl << 2));
    #pragma unroll
    for (int j = 0; j < 16; ++j){
      if (i + j < deg){
        ax += bf2f((unsigned short)(v[j] & 0xFFFFu));
        ay += bf2f((unsigned short)(v[j] >> 16));
      }
    }
  }
  float nrm = deg > 0 ? rsqrtf((float)deg) : 1.0f;
  unsigned int pv = (unsigned int)f2bf(ax*nrm) | ((unsigned int)f2bf(ay*nrm) << 16);
  __builtin_nontemporal_store(pv, (unsigned int*)(agg + ((size_t)row << 6)) + hl);
}

// ---- GEMM: H = Xd@W[0:64] + Agg@W[64:128] + b, prepacked B frags, fused BN stats ----
__global__ __launch_bounds__(256) void gemm2_k(const unsigned short* __restrict__ Agg,
                                               const unsigned short* __restrict__ Xd,
                                               const unsigned short* __restrict__ Wp,
                                               const float* __restrict__ bias,
                                               unsigned short* __restrict__ Hout,
                                               float* __restrict__ stats){
  __shared__ float ls[128];
  for (int t0 = threadIdx.x; t0 < 128; t0 += 256) ls[t0] = 0.0f;
  __syncthreads();
  int lane = threadIdx.x & 63;
  int gw = (int)((blockIdx.x*256 + threadIdx.x) >> 6);
  int nw = (int)(gridDim.x * 4);
  int c16 = lane & 15, kg = lane >> 4;

  short8v Bf[2][2][4];
  #pragma unroll
  for (int s = 0; s < 2; ++s)
    #pragma unroll
    for (int t2 = 0; t2 < 2; ++t2)
      #pragma unroll
      for (int c = 0; c < 4; ++c)
        Bf[s][t2][c] = ((const short8v*)Wp)[(((s*2 + t2)*4 + c)*4 + kg)*16 + c16];
  float bc[4];
  #pragma unroll
  for (int c = 0; c < 4; ++c) bc[c] = bias[c*16 + c16];

  float ssum[4] = {0,0,0,0}, ssq[4] = {0,0,0,0};
  const int ntile = RN/16;
  for (int tile = gw; tile < ntile; tile += nw){
    int r0 = tile*16;
    int ar = r0 + c16;
    short8v A00 = ((const short8v*)Xd)[ar*8 + kg];
    short8v A01 = ((const short8v*)Xd)[ar*8 + 4 + kg];
    short8v A10 = ((const short8v*)Agg)[ar*8 + kg];
    short8v A11 = ((const short8v*)Agg)[ar*8 + 4 + kg];
    f32x4 acc4[4];
    #pragma unroll
    for (int c = 0; c < 4; ++c){ f32x4 z = {bc[c],bc[c],bc[c],bc[c]}; acc4[c] = z; }
    #pragma unroll
    for (int c = 0; c < 4; ++c){
      acc4[c] = __builtin_amdgcn_mfma_f32_16x16x32_bf16(A00, Bf[0][0][c], acc4[c], 0, 0, 0);
      acc4[c] = __builtin_amdgcn_mfma_f32_16x16x32_bf16(A01, Bf[0][1][c], acc4[c], 0, 0, 0);
      acc4[c] = __builtin_amdgcn_mfma_f32_16x16x32_bf16(A10, Bf[1][0][c], acc4[c], 0, 0, 0);
      acc4[c] = __builtin_amdgcn_mfma_f32_16x16x32_bf16(A11, Bf[1][1][c], acc4[c], 0, 0, 0);
    }
    int orow = r0 + kg*4;   // C layout: col = lane&15, row = (lane>>4)*4 + reg [m89]
    #pragma unroll
    for (int c = 0; c < 4; ++c)
      #pragma unroll
      for (int r = 0; r < 4; ++r){
        float v = acc4[c][r];
        ssum[c] += v; ssq[c] += v*v;
        __builtin_nontemporal_store(f2bf(v), &Hout[(size_t)(orow + r)*DIM + c*16 + c16]);
      }
  }
  #pragma unroll
  for (int c = 0; c < 4; ++c){
    atomicAdd(&ls[c*16 + c16], ssum[c]);
    atomicAdd(&ls[64 + c*16 + c16], ssq[c]);
  }
  __syncthreads();
  for (int t0 = threadIdx.x; t0 < 128; t0 += 256) atomicAdd(&stats[t0], ls[t0]);
}

// ---- BN finalize for both halves of a layer ----
__global__ __launch_bounds__(128) void bnfin2_k(const float* stats,
                                                const float* gI, const float* beI, float* acI,
                                                const float* gU, const float* beU, float* acU){
  int t = threadIdx.x, j = t & 63;
  const float* st = (t < 64) ? stats : stats + 128;
  float mu  = st[j]    * (1.0f/RN);
  float var = st[64+j] * (1.0f/RN) - mu*mu;
  float inv = rsqrtf(var + 1e-5f);
  if (t < 64){ float a = gI[j]*inv; acI[j] = a; acI[64+j] = beI[j] - mu*a; }
  else       { float a = gU[j]*inv; acU[j] = a; acU[64+j] = beU[j] - mu*a; }
}

// ---- BN + SiLU in-place over the union buffer (users half then items half) ----
__global__ __launch_bounds__(256) void bnapply2_k(unsigned short* H,
                                                  const float* __restrict__ acU,
                                                  const float* __restrict__ acI, int n8){
  int i = blockIdx.x*256 + threadIdx.x;
  if (i >= n8) return;
  const float* ac = (i < RN*8) ? acU : acI;
  us8 v = ((us8*)H)[i];
  int cb = (i*8) & 63;
  #pragma unroll
  for (int r = 0; r < 8; ++r){
    float x = bf2f(v[r]);
    float y = ac[cb+r]*x + ac[64+cb+r];
    float o = y / (1.0f + expf(-y));
    v[r] = f2bf(o);
  }
  ((us8*)H)[i] = v;
}

// ---- BN + SiLU to d_out; user rows from Hu, item rows from Hi ----
__global__ __launch_bounds__(256) void bnout2_k(const unsigned short* __restrict__ Hu,
                                                const unsigned short* __restrict__ Hi,
                                                const float* __restrict__ acU,
                                                const float* __restrict__ acI,
                                                void* out, const int* __restrict__ flags, int n8){
  int i = blockIdx.x*256 + threadIdx.x;
  if (i >= n8) return;
  int item = (i >= RN*8);
  const float* ac = item ? acI : acU;
  us8 v = item ? ((const us8*)Hi)[i - RN*8] : ((const us8*)Hu)[i];
  int cb = (i*8) & 63;
  float o[8];
  #pragma unroll
  for (int r = 0; r < 8; ++r){
    float x = bf2f(v[r]);
    float y = ac[cb+r]*x + ac[64+cb+r];
    o[r] = y / (1.0f + expf(-y));
  }
  if (flags[0]){
    unsigned short* ob = (unsigned short*)out + (size_t)i*8;
    us8 wv;
    #pragma unroll
    for (int r = 0; r < 8; ++r) wv[r] = f2bf(o[r]);
    __builtin_nontemporal_store(wv, (us8*)ob);
  } else {
    float* ob = (float*)out + (size_t)i*8;
    f32x4 w0 = {o[0],o[1],o[2],o[3]}, w1 = {o[4],o[5],o[6],o[7]};
    __builtin_nontemporal_store(w0, (f32x4*)ob);
    __builtin_nontemporal_store(w1, (f32x4*)ob + 1);
  }
}

extern "C" void kernel_launch(void* const* d_in, const int* in_sizes, int n_in,
                              void* d_out, int out_size, void* d_ws, size_t ws_size,
                              hipStream_t stream){
  (void)in_sizes; (void)n_in; (void)out_size;
  const void* user_emb = d_in[0];
  const void* item_emb = d_in[1];
  const void* go_src   = d_in[18];
  const void* go_dst   = d_in[19];
  const void* back_src = d_in[20];
  const void* back_dst = d_in[21];

  char* ws = (char*)d_ws;
  size_t off = 0;
  auto alloc = [&](size_t bytes) -> void* {
    void* p = ws + off;
    off += (bytes + 255) & ~((size_t)255);
    return p;
  };
  int*   flags  = (int*)  alloc(64);
  float* params = (float*)alloc((size_t)49920*4);
  unsigned short* wpack = (unsigned short*)alloc((size_t)4*8192*2);
  float* bnac   = (float*)alloc(512*4);
  float* stats  = (float*)alloc(512*4);
  int*   Cmat   = (int*)  alloc((size_t)NBB*NBLKP*4);
  int*   Rloc   = (int*)  alloc((size_t)NBB*NBLKP*4);
  int*   Sbuf   = (int*)  alloc(1024*4);
  int*   s0g    = (int*)  alloc(1024*4);
  int*   rs_all = (int*)  alloc((size_t)(NR2+1)*4);
  int*   col_all= (int*)  alloc(((size_t)2*NE + 64)*4);              // +64 pad: deg-0 tail reads
  unsigned short* x1   = (unsigned short*)alloc((size_t)NR2*DIM*2);  // embeddings -> later agg2/h2u
  unsigned short* x2   = (unsigned short*)alloc((size_t)NR2*DIM*2);  // layer-1 output (silu'd in place)
  unsigned short* agg1 = (unsigned short*)alloc((size_t)RN*DIM*2);   // per-relation agg -> later h2i
  if (off > ws_size) return;  // visible as absmax == 5.8125

  unsigned int* slab = (unsigned int*)x2;   // 8MB alias; dead before gemm writes x2
  unsigned short* agg2 = x1;                // layer-2 agg (x1 dead after layer-1 gemms)
  unsigned short* h2i  = agg1;              // layer-2 go output (items)
  unsigned short* h2u  = x1;                // layer-2 back output (users) over agg2's dead go half

  int* rs_go = rs_all;
  int* rs_bk = rs_all + RN;
  unsigned short* x1u = x1;
  unsigned short* x1i = x1 + (size_t)RN*DIM;
  unsigned short* x2u = x2;
  unsigned short* x2i = x2 + (size_t)RN*DIM;

  const int G8A = (NR2*DIM/8)/256;          // 12500
  const int GS3 = RN/8;                     // 25000 blocks: 8 rows per block (2/wave)

  float* b_go1 = params + 12288;
  float* b_bk1 = params + 24640;
  float* b_go2 = params + 36992;
  float* b_bk2 = params + 49344;
  float* g1u = params + 49408; float* be1u = params + 49472;
  float* g1i = params + 49536; float* be1i = params + 49600;
  float* g2u = params + 49664; float* be2u = params + 49728;
  float* g2i = params + 49792; float* be2i = params + 49856;

  Ptrs16 ps;
  for (int i = 0; i < 16; ++i) ps.p[i] = d_in[2+i];

  detect2_k<<<1,256,0,stream>>>((const unsigned short*)user_emb, (const unsigned int*)go_src,
                                flags, ps, params, stats);
  prepack_k<<<128,256,0,stream>>>(ps, flags, wpack);
  conv_emb2_k<<<G8A,256,0,stream>>>(user_emb, item_emb, x1, flags, NR2*DIM/8);

  // ---- CSR build (block-local counting sort; validated R5; union col) ----
  pass1_k<<<NBLK,256,0,stream>>>((const unsigned int*)go_dst, (const unsigned int*)back_dst,
                                 Cmat, Rloc, flags);
  sizes_k<<<(NBB+3)/4,256,0,stream>>>(Cmat, Sbuf);
  scanS_k<<<1,1024,0,stream>>>(Sbuf, s0g, rs_all);
  pass2_k<<<NBLK,256,0,stream>>>((const unsigned int*)go_src, (const unsigned int*)go_dst,
                                 (const unsigned int*)back_src, (const unsigned int*)back_dst,
                                 Rloc, slab, flags);
  buildCSR2_k<<<NBB,512,0,stream>>>(Cmat, Rloc, s0g, slab, rs_all, col_all);

  // ---- layer 1 (per relation: spmm -> agg1, gemm -> x2 half + stats) ----
  spmm3_k<<<GS3,256,0,stream>>>(rs_go, col_all, x1, agg1, RN);
  gemm2_k<<<1024,256,0,stream>>>(agg1, x1i, wpack + 0*8192, b_go1, x2i, stats + 0);
  spmm3_k<<<GS3,256,0,stream>>>(rs_bk, col_all, x1, agg1, RN);
  gemm2_k<<<1024,256,0,stream>>>(agg1, x1u, wpack + 1*8192, b_bk1, x2u, stats + 128);
  bnfin2_k<<<1,128,0,stream>>>(stats + 0, g1i, be1i, bnac + 0, g1u, be1u, bnac + 128);

  // ---- layer 2: materialize silu(x2), two per-relation spmms, gemms, output ----
  bnapply2_k<<<G8A,256,0,stream>>>(x2, bnac + 128, bnac + 0, NR2*DIM/8);
  spmm3_k<<<GS3,256,0,stream>>>(rs_go, col_all, x2, agg2, RN);
  spmm3_k<<<GS3,256,0,stream>>>(rs_bk, col_all, x2, agg2 + (size_t)RN*DIM, RN);
  gemm2_k<<<1024,256,0,stream>>>(agg2, x2i, wpack + 2*8192, b_go2, h2i, stats + 256);
  gemm2_k<<<1024,256,0,stream>>>(agg2 + (size_t)RN*DIM, x2u, wpack + 3*8192, b_bk2, h2u, stats + 384);
  bnfin2_k<<<1,128,0,stream>>>(stats + 256, g2i, be2i, bnac + 256, g2u, be2u, bnac + 384);
  bnout2_k<<<G8A,256,0,stream>>>(h2u, h2i, bnac + 384, bnac + 256, d_out, flags, NR2*DIM/8);
}

// Round 11
// 448.059 us; speedup vs baseline: 1.3566x; 1.1244x over previous
//
#include <hip/hip_runtime.h>
#include <cstdint>
#include <cstddef>

#define RN 200000   // nodes per side (NU == NI)
#define NR2 400000  // both sides
#define DIM 64
#define NE 1000000  // edges per relation
#define NB_PR 391   // buckets per relation (512 rows each)
#define NBB 782     // total buckets (go: 0..390, back: 391..781)
#define ET 4096     // edges per sort block
#define NBLK 489    // ceil(2*NE / ET)
#define NBLKP 512   // padded row length of C/Rloc (bucket-major)

typedef __attribute__((ext_vector_type(8))) short short8v;   // 8 x bf16 (4 VGPR)
typedef __attribute__((ext_vector_type(4))) float f32x4;
typedef __attribute__((ext_vector_type(8))) unsigned short us8;
typedef __attribute__((ext_vector_type(2))) unsigned int uint2v;

struct Ptrs16 { const void* p[16]; };

__device__ __forceinline__ float bf2f(unsigned short u){
  unsigned int x = ((unsigned int)u) << 16;
  return __builtin_bit_cast(float, x);
}
__device__ __forceinline__ unsigned short f2bf(float f){
  unsigned int x = __builtin_bit_cast(unsigned int, f);
  unsigned int r = x + 0x7fffu + ((x >> 16) & 1u);   // RNE
  return (unsigned short)(r >> 16);
}

// ---- dtype sniff + small-param convert + stats zero (single block) ----
__global__ __launch_bounds__(256) void detect2_k(const unsigned short* emb,
                                                 const unsigned int* esrc,
                                                 int* flags, Ptrs16 ps,
                                                 float* params, float* stats){
  __shared__ int cnt0, cnt1, sf0;
  int t = threadIdx.x;
  if (t == 0){ cnt0 = 0; cnt1 = 0; }
  __syncthreads();
  int c0 = 0, c1 = 0;
  #pragma unroll
  for (int s = 0; s < 4; ++s){
    int i = (t*4 + s) * 14;
    float af = fabsf(bf2f(emb[i]));
    if (af > 0.0009765625f && af < 32.0f) c0++;
    int e = t*4 + s;
    if (esrc[2*e + 1] != 0u) c1++;
  }
  atomicAdd(&cnt0, c0); atomicAdd(&cnt1, c1);
  __syncthreads();
  if (t == 0){
    int f0 = (cnt0 > 512) ? 1 : 0;
    int f1 = (cnt1 < 512) ? 1 : 0;
    flags[0] = f0; flags[1] = f1; sf0 = f0;
  }
  __syncthreads();
  int f0 = sf0;
  const int aidx[12] = {1,3,5,7,8,9,10,11,12,13,14,15};
  const int aoff[12] = {12288,24640,36992,49344,49408,49472,49536,49600,49664,49728,49792,49856};
  for (int base = t; base < 768; base += 256){
    int a = base >> 6, j = base & 63;
    const void* p = ps.p[aidx[a]];
    params[aoff[a] + j] = f0 ? bf2f(((const unsigned short*)p)[j]) : ((const float*)p)[j];
  }
  for (int z = t; z < 512; z += 256) stats[z] = 0.0f;
}

// ---- prepack the 4 weight matrices (raw inputs) into MFMA fragment order ----
__global__ __launch_bounds__(256) void prepack_k(Ptrs16 ps, const int* flags,
                                                 unsigned short* __restrict__ wpack){
  int i = blockIdx.x*256 + threadIdx.x;
  if (i >= 4*8192) return;
  int m = i >> 13, f = i & 8191;
  int r   = f & 7;
  int c16 = (f >> 3) & 15;
  int kg  = (f >> 7) & 3;
  int c   = (f >> 9) & 3;
  int t2  = (f >> 11) & 1;
  int s   = (f >> 12) & 1;
  int k = s*64 + t2*32 + kg*8 + r;
  int j = k*DIM + c*16 + c16;
  const void* wp = ps.p[m*2];          // W_go1, W_back1, W_go2, W_back2
  float v = flags[0] ? bf2f(((const unsigned short*)wp)[j]) : ((const float*)wp)[j];
  wpack[i] = f2bf(v);
}

// ---- canonicalize both embeddings into union bf16 buffer x1 (users, then items) ----
__global__ __launch_bounds__(256) void conv_emb2_k(const void* uin, const void* iin,
                                                   unsigned short* out,
                                                   const int* flags, int n8){
  int i = blockIdx.x*256 + threadIdx.x;
  if (i >= n8) return;
  int item = (i >= RN*8);
  const void* in = item ? iin : uin;
  int li = item ? i - RN*8 : i;
  us8 o;
  if (flags[0]){
    o = ((const us8*)in)[li];
  } else {
    const float* f = (const float*)in + (size_t)li*8;
    #pragma unroll
    for (int r = 0; r < 8; ++r) o[r] = f2bf(f[r]);
  }
  ((us8*)out)[i] = o;
}

// ==== CSR build R10: single-read merged histogram + scatter ====
// Decode 2M edges ONCE: LDS-stage (packed, bucket), LDS histogram -> scan ->
// write C/Rloc -> LDS-cursor scatter into the block's private slab region.
__global__ __launch_bounds__(256) void pass12_k(const unsigned int* go_src, const unsigned int* go_dst,
                                                const unsigned int* back_src, const unsigned int* back_dst,
                                                int* __restrict__ C, int* __restrict__ Rloc,
                                                unsigned int* __restrict__ slab, const int* flags){
  __shared__ unsigned int spk[ET];      // 16KB: src | row_in_bucket<<18
  __shared__ unsigned short sbk[ET];    // 8KB: bucket id (0xFFFF = invalid)
  __shared__ int h[1024];               // histogram -> cursors
  __shared__ int ps[256];
  int blk = blockIdx.x, t = threadIdx.x;
  #pragma unroll
  for (int q = 0; q < 4; ++q) h[t + q*256] = 0;
  __syncthreads();
  int i64 = flags[1];
  int e0 = blk*ET;
  #pragma unroll
  for (int j = 0; j < 16; ++j){
    int e = e0 + j*256 + t;
    int li = j*256 + t;
    if (e < 2*NE){
      int rel = e >= NE;
      int ei = rel ? e - NE : e;
      const unsigned int* pd = rel ? back_dst : go_dst;
      const unsigned int* psr = rel ? back_src : go_src;
      int d  = i64 ? (int)pd[2*ei]  : (int)pd[ei];
      int sc = i64 ? (int)psr[2*ei] : (int)psr[ei];
      int b = (rel ? NB_PR : 0) + (d >> 9);
      spk[li] = (unsigned)sc | ((unsigned)(d & 511) << 18);
      sbk[li] = (unsigned short)b;
      atomicAdd(&h[b], 1);
    } else {
      sbk[li] = 0xFFFFu;
    }
  }
  __syncthreads();
  int c4[4], p4[4]; int s = 0;
  #pragma unroll
  for (int q = 0; q < 4; ++q){ c4[q] = h[t*4 + q]; p4[q] = s; s += c4[q]; }
  ps[t] = s;
  __syncthreads();
  for (int o = 1; o < 256; o <<= 1){
    int x = (t >= o) ? ps[t-o] : 0;
    __syncthreads();
    ps[t] += x;
    __syncthreads();
  }
  int base = (t > 0) ? ps[t-1] : 0;
  #pragma unroll
  for (int q = 0; q < 4; ++q){
    int b = t*4 + q;
    if (b < NBB){
      C[b*NBLKP + blk]    = c4[q];
      Rloc[b*NBLKP + blk] = base + p4[q];
    }
  }
  __syncthreads();                       // scan reads done; reuse h as cursors
  #pragma unroll
  for (int q = 0; q < 4; ++q){
    int b = t*4 + q;
    h[b] = base + p4[q];
  }
  __syncthreads();
  #pragma unroll
  for (int j = 0; j < 16; ++j){
    int li = j*256 + t;
    unsigned short b = sbk[li];
    if (b != 0xFFFFu){
      int pos = atomicAdd(&h[b], 1);
      slab[(size_t)blk*ET + pos] = spk[li];
    }
  }
}

__global__ __launch_bounds__(256) void sizes_k(const int* __restrict__ C, int* __restrict__ S){
  int w = blockIdx.x*4 + (threadIdx.x >> 6);
  int lane = threadIdx.x & 63;
  if (w >= NBB) return;
  int sum = 0;
  for (int k = lane; k < NBLK; k += 64) sum += C[w*NBLKP + k];
  #pragma unroll
  for (int o = 32; o > 0; o >>= 1) sum += __shfl_down(sum, o, 64);
  if (lane == 0) S[w] = sum;
}

__global__ __launch_bounds__(1024) void scanS_k(const int* __restrict__ S, int* __restrict__ s0,
                                                int* __restrict__ rs){
  __shared__ int sh[1024];
  int t = threadIdx.x;
  int v = (t < NBB) ? S[t] : 0;
  sh[t] = v;
  __syncthreads();
  for (int o = 1; o < 1024; o <<= 1){
    int x = (t >= o) ? sh[t-o] : 0;
    __syncthreads();
    sh[t] += x;
    __syncthreads();
  }
  if (t < NBB) s0[t] = sh[t] - v;
  if (t == NBB-1){ s0[NBB] = sh[t]; rs[NR2] = 2*NE; }
}

// col written in UNION space (+RN for back-relation sources = items)
__global__ __launch_bounds__(512) void buildCSR2_k(const int* __restrict__ C,
                                                   const int* __restrict__ Rloc,
                                                   const int* __restrict__ s0g,
                                                   const unsigned int* __restrict__ slab,
                                                   int* __restrict__ rs, int* __restrict__ col){
  __shared__ int cblk[NBLKP], rblk[NBLKP], off[NBLKP];
  __shared__ int lcnt[512], lsc[512], lcur[512];
  int b = blockIdx.x, t = threadIdx.x;
  cblk[t] = (t < NBLK) ? C[b*NBLKP + t] : 0;
  rblk[t] = (t < NBLK) ? Rloc[b*NBLKP + t] : 0;
  lcnt[t] = 0;
  int v = cblk[t];
  off[t] = v;
  __syncthreads();
  for (int o = 1; o < 512; o <<= 1){
    int x = (t >= o) ? off[t-o] : 0;
    __syncthreads();
    off[t] += x;
    __syncthreads();
  }
  int Sb = off[511];
  int excl = off[t] - v;
  __syncthreads();
  off[t] = excl;
  __syncthreads();
  int s0b = s0g[b];
  int d0 = (b < NB_PR) ? b*512 : RN + (b - NB_PR)*512;
  int relEnd = (b < NB_PR) ? RN : NR2;
  int rows = relEnd - d0; if (rows > 512) rows = 512;
  int srcoff = (b < NB_PR) ? 0 : RN;       // union-space source offset
  for (int i = t; i < Sb; i += 512){
    int lo = 0;
    #pragma unroll
    for (int st = 256; st > 0; st >>= 1){
      int nx = lo + st;
      if (nx < 512 && off[nx] <= i) lo = nx;
    }
    unsigned int q = slab[(size_t)lo*ET + rblk[lo] + (i - off[lo])];
    atomicAdd(&lcnt[q >> 18], 1);
  }
  __syncthreads();
  int rv = lcnt[t];
  lsc[t] = rv;
  __syncthreads();
  for (int o = 1; o < 512; o <<= 1){
    int x = (t >= o) ? lsc[t-o] : 0;
    __syncthreads();
    lsc[t] += x;
    __syncthreads();
  }
  int start = lsc[t] - rv;
  lcur[t] = start;
  if (t < rows) rs[d0 + t] = s0b + start;
  __syncthreads();
  for (int i = t; i < Sb; i += 512){
    int lo = 0;
    #pragma unroll
    for (int st = 256; st > 0; st >>= 1){
      int nx = lo + st;
      if (nx < 512 && off[nx] <= i) lo = nx;
    }
    unsigned int q = slab[(size_t)lo*ET + rblk[lo] + (i - off[lo])];
    int r = (int)(q >> 18);
    int p = atomicAdd(&lcur[r], 1);
    col[s0b + p] = (int)(q & 0x3FFFFu) + srcoff;
  }
}

// ---- SpMM R10: QUARTER-WAVE per dst row. 16 lanes x 8 B (4 bf16) per row,
// 4 rows/wave, 16-deep batches -> 8 KB/wave in flight. Tail clamps to edge 0. ----
__global__ __launch_bounds__(256) void spmm4_k(const int* __restrict__ rs, const int* __restrict__ col,
                                               const unsigned short* __restrict__ Xg,
                                               unsigned short* __restrict__ agg, int nrows){
  int wv = (int)((blockIdx.x*256 + threadIdx.x) >> 6);
  int lane = threadIdx.x & 63;
  int hl = lane & 15;
  int row = wv*4 + (lane >> 4);
  if (row >= nrows) return;
  int b = rs[row], e = rs[row+1];      // uniform within quarter (broadcast loads)
  int deg = e - b;
  int dq0 = __shfl(deg, 0), dq1 = __shfl(deg, 16);
  int dq2 = __shfl(deg, 32), dq3 = __shfl(deg, 48);
  int md = max(max(dq0, dq1), max(dq2, dq3));   // wave-uniform trip bound
  float a0 = 0, a1 = 0, a2 = 0, a3 = 0;
  for (int i = 0; i < md; i += 16){
    int idx[16];
    #pragma unroll
    for (int j = 0; j < 16; ++j){
      int o = i + j;
      int cid = b + ((o < deg) ? o : 0);
      int ix = col[cid];
      idx[j] = ((unsigned)ix < (unsigned)NR2) ? ix : 0;   // safety clamp
    }
    uint2v v[16];
    #pragma unroll
    for (int j = 0; j < 16; ++j)
      v[j] = *(const uint2v*)((const char*)Xg + (((size_t)(unsigned)idx[j]) << 7) + (hl << 3));
    #pragma unroll
    for (int j = 0; j < 16; ++j){
      if (i + j < deg){
        a0 += bf2f((unsigned short)(v[j].x & 0xFFFFu));
        a1 += bf2f((unsigned short)(v[j].x >> 16));
        a2 += bf2f((unsigned short)(v[j].y & 0xFFFFu));
        a3 += bf2f((unsigned short)(v[j].y >> 16));
      }
    }
  }
  float nrm = deg > 0 ? rsqrtf((float)deg) : 1.0f;
  uint2v pv;
  pv.x = (unsigned)f2bf(a0*nrm) | ((unsigned)f2bf(a1*nrm) << 16);
  pv.y = (unsigned)f2bf(a2*nrm) | ((unsigned)f2bf(a3*nrm) << 16);
  __builtin_nontemporal_store(pv, (uint2v*)(agg + ((size_t)row << 6)) + hl);
}

// ---- GEMM: H = Xd@W[0:64] + Agg@W[64:128] + b, prepacked B frags, fused BN stats ----
__global__ __launch_bounds__(256) void gemm2_k(const unsigned short* __restrict__ Agg,
                                               const unsigned short* __restrict__ Xd,
                                               const unsigned short* __restrict__ Wp,
                                               const float* __restrict__ bias,
                                               unsigned short* __restrict__ Hout,
                                               float* __restrict__ stats){
  __shared__ float ls[128];
  for (int t0 = threadIdx.x; t0 < 128; t0 += 256) ls[t0] = 0.0f;
  __syncthreads();
  int lane = threadIdx.x & 63;
  int gw = (int)((blockIdx.x*256 + threadIdx.x) >> 6);
  int nw = (int)(gridDim.x * 4);
  int c16 = lane & 15, kg = lane >> 4;

  short8v Bf[2][2][4];
  #pragma unroll
  for (int s = 0; s < 2; ++s)
    #pragma unroll
    for (int t2 = 0; t2 < 2; ++t2)
      #pragma unroll
      for (int c = 0; c < 4; ++c)
        Bf[s][t2][c] = ((const short8v*)Wp)[(((s*2 + t2)*4 + c)*4 + kg)*16 + c16];
  float bc[4];
  #pragma unroll
  for (int c = 0; c < 4; ++c) bc[c] = bias[c*16 + c16];

  float ssum[4] = {0,0,0,0}, ssq[4] = {0,0,0,0};
  const int ntile = RN/16;
  for (int tile = gw; tile < ntile; tile += nw){
    int r0 = tile*16;
    int ar = r0 + c16;
    short8v A00 = ((const short8v*)Xd)[ar*8 + kg];
    short8v A01 = ((const short8v*)Xd)[ar*8 + 4 + kg];
    short8v A10 = ((const short8v*)Agg)[ar*8 + kg];
    short8v A11 = ((const short8v*)Agg)[ar*8 + 4 + kg];
    f32x4 acc4[4];
    #pragma unroll
    for (int c = 0; c < 4; ++c){ f32x4 z = {bc[c],bc[c],bc[c],bc[c]}; acc4[c] = z; }
    #pragma unroll
    for (int c = 0; c < 4; ++c){
      acc4[c] = __builtin_amdgcn_mfma_f32_16x16x32_bf16(A00, Bf[0][0][c], acc4[c], 0, 0, 0);
      acc4[c] = __builtin_amdgcn_mfma_f32_16x16x32_bf16(A01, Bf[0][1][c], acc4[c], 0, 0, 0);
      acc4[c] = __builtin_amdgcn_mfma_f32_16x16x32_bf16(A10, Bf[1][0][c], acc4[c], 0, 0, 0);
      acc4[c] = __builtin_amdgcn_mfma_f32_16x16x32_bf16(A11, Bf[1][1][c], acc4[c], 0, 0, 0);
    }
    int orow = r0 + kg*4;   // C layout: col = lane&15, row = (lane>>4)*4 + reg [m89]
    #pragma unroll
    for (int c = 0; c < 4; ++c)
      #pragma unroll
      for (int r = 0; r < 4; ++r){
        float v = acc4[c][r];
        ssum[c] += v; ssq[c] += v*v;
        __builtin_nontemporal_store(f2bf(v), &Hout[(size_t)(orow + r)*DIM + c*16 + c16]);
      }
  }
  #pragma unroll
  for (int c = 0; c < 4; ++c){
    atomicAdd(&ls[c*16 + c16], ssum[c]);
    atomicAdd(&ls[64 + c*16 + c16], ssq[c]);
  }
  __syncthreads();
  for (int t0 = threadIdx.x; t0 < 128; t0 += 256) atomicAdd(&stats[t0], ls[t0]);
}

// ---- BN finalize for both halves of a layer ----
__global__ __launch_bounds__(128) void bnfin2_k(const float* stats,
                                                const float* gI, const float* beI, float* acI,
                                                const float* gU, const float* beU, float* acU){
  int t = threadIdx.x, j = t & 63;
  const float* st = (t < 64) ? stats : stats + 128;
  float mu  = st[j]    * (1.0f/RN);
  float var = st[64+j] * (1.0f/RN) - mu*mu;
  float inv = rsqrtf(var + 1e-5f);
  if (t < 64){ float a = gI[j]*inv; acI[j] = a; acI[64+j] = beI[j] - mu*a; }
  else       { float a = gU[j]*inv; acU[j] = a; acU[64+j] = beU[j] - mu*a; }
}

// ---- BN + SiLU in-place over the union buffer (users half then items half) ----
__global__ __launch_bounds__(256) void bnapply2_k(unsigned short* H,
                                                  const float* __restrict__ acU,
                                                  const float* __restrict__ acI, int n8){
  int i = blockIdx.x*256 + threadIdx.x;
  if (i >= n8) return;
  const float* ac = (i < RN*8) ? acU : acI;
  us8 v = ((us8*)H)[i];
  int cb = (i*8) & 63;
  #pragma unroll
  for (int r = 0; r < 8; ++r){
    float x = bf2f(v[r]);
    float y = ac[cb+r]*x + ac[64+cb+r];
    float o = y / (1.0f + expf(-y));
    v[r] = f2bf(o);
  }
  ((us8*)H)[i] = v;
}

// ---- BN + SiLU to d_out; user rows from Hu, item rows from Hi ----
__global__ __launch_bounds__(256) void bnout2_k(const unsigned short* __restrict__ Hu,
                                                const unsigned short* __restrict__ Hi,
                                                const float* __restrict__ acU,
                                                const float* __restrict__ acI,
                                                void* out, const int* __restrict__ flags, int n8){
  int i = blockIdx.x*256 + threadIdx.x;
  if (i >= n8) return;
  int item = (i >= RN*8);
  const float* ac = item ? acI : acU;
  us8 v = item ? ((const us8*)Hi)[i - RN*8] : ((const us8*)Hu)[i];
  int cb = (i*8) & 63;
  float o[8];
  #pragma unroll
  for (int r = 0; r < 8; ++r){
    float x = bf2f(v[r]);
    float y = ac[cb+r]*x + ac[64+cb+r];
    o[r] = y / (1.0f + expf(-y));
  }
  if (flags[0]){
    unsigned short* ob = (unsigned short*)out + (size_t)i*8;
    us8 wv;
    #pragma unroll
    for (int r = 0; r < 8; ++r) wv[r] = f2bf(o[r]);
    __builtin_nontemporal_store(wv, (us8*)ob);
  } else {
    float* ob = (float*)out + (size_t)i*8;
    f32x4 w0 = {o[0],o[1],o[2],o[3]}, w1 = {o[4],o[5],o[6],o[7]};
    __builtin_nontemporal_store(w0, (f32x4*)ob);
    __builtin_nontemporal_store(w1, (f32x4*)ob + 1);
  }
}

extern "C" void kernel_launch(void* const* d_in, const int* in_sizes, int n_in,
                              void* d_out, int out_size, void* d_ws, size_t ws_size,
                              hipStream_t stream){
  (void)in_sizes; (void)n_in; (void)out_size;
  const void* user_emb = d_in[0];
  const void* item_emb = d_in[1];
  const void* go_src   = d_in[18];
  const void* go_dst   = d_in[19];
  const void* back_src = d_in[20];
  const void* back_dst = d_in[21];

  char* ws = (char*)d_ws;
  size_t off = 0;
  auto alloc = [&](size_t bytes) -> void* {
    void* p = ws + off;
    off += (bytes + 255) & ~((size_t)255);
    return p;
  };
  int*   flags  = (int*)  alloc(64);
  float* params = (float*)alloc((size_t)49920*4);
  unsigned short* wpack = (unsigned short*)alloc((size_t)4*8192*2);
  float* bnac   = (float*)alloc(512*4);
  float* stats  = (float*)alloc(512*4);
  int*   Cmat   = (int*)  alloc((size_t)NBB*NBLKP*4);
  int*   Rloc   = (int*)  alloc((size_t)NBB*NBLKP*4);
  int*   Sbuf   = (int*)  alloc(1024*4);
  int*   s0g    = (int*)  alloc(1024*4);
  int*   rs_all = (int*)  alloc((size_t)(NR2+1)*4);
  int*   col_all= (int*)  alloc(((size_t)2*NE + 64)*4);              // +64 pad: deg-0 tail reads
  unsigned short* x1   = (unsigned short*)alloc((size_t)NR2*DIM*2);  // embeddings -> later agg2/h2u
  unsigned short* x2   = (unsigned short*)alloc((size_t)NR2*DIM*2);  // layer-1 output (silu'd in place)
  unsigned short* agg1 = (unsigned short*)alloc((size_t)RN*DIM*2);   // per-relation agg -> later h2i
  if (off > ws_size) return;  // visible as absmax == 5.8125

  unsigned int* slab = (unsigned int*)x2;   // 8MB alias; dead before gemm writes x2
  unsigned short* agg2 = x1;                // layer-2 agg (x1 dead after layer-1 gemms)
  unsigned short* h2i  = agg1;              // layer-2 go output (items)
  unsigned short* h2u  = x1;                // layer-2 back output (users) over agg2's dead go half

  int* rs_go = rs_all;
  int* rs_bk = rs_all + RN;
  unsigned short* x1u = x1;
  unsigned short* x1i = x1 + (size_t)RN*DIM;
  unsigned short* x2u = x2;
  unsigned short* x2i = x2 + (size_t)RN*DIM;

  const int G8A = (NR2*DIM/8)/256;          // 12500
  const int GS4 = RN/16;                    // 12500 blocks: 16 rows per block (4/wave)

  float* b_go1 = params + 12288;
  float* b_bk1 = params + 24640;
  float* b_go2 = params + 36992;
  float* b_bk2 = params + 49344;
  float* g1u = params + 49408; float* be1u = params + 49472;
  float* g1i = params + 49536; float* be1i = params + 49600;
  float* g2u = params + 49664; float* be2u = params + 49728;
  float* g2i = params + 49792; float* be2i = params + 49856;

  Ptrs16 ps;
  for (int i = 0; i < 16; ++i) ps.p[i] = d_in[2+i];

  detect2_k<<<1,256,0,stream>>>((const unsigned short*)user_emb, (const unsigned int*)go_src,
                                flags, ps, params, stats);
  prepack_k<<<128,256,0,stream>>>(ps, flags, wpack);
  conv_emb2_k<<<G8A,256,0,stream>>>(user_emb, item_emb, x1, flags, NR2*DIM/8);

  // ---- CSR build (merged single-read counting sort; union col) ----
  pass12_k<<<NBLK,256,0,stream>>>((const unsigned int*)go_src, (const unsigned int*)go_dst,
                                  (const unsigned int*)back_src, (const unsigned int*)back_dst,
                                  Cmat, Rloc, slab, flags);
  sizes_k<<<(NBB+3)/4,256,0,stream>>>(Cmat, Sbuf);
  scanS_k<<<1,1024,0,stream>>>(Sbuf, s0g, rs_all);
  buildCSR2_k<<<NBB,512,0,stream>>>(Cmat, Rloc, s0g, slab, rs_all, col_all);

  // ---- layer 1 (per relation: spmm -> agg1, gemm -> x2 half + stats) ----
  spmm4_k<<<GS4,256,0,stream>>>(rs_go, col_all, x1, agg1, RN);
  gemm2_k<<<1024,256,0,stream>>>(agg1, x1i, wpack + 0*8192, b_go1, x2i, stats + 0);
  spmm4_k<<<GS4,256,0,stream>>>(rs_bk, col_all, x1, agg1, RN);
  gemm2_k<<<1024,256,0,stream>>>(agg1, x1u, wpack + 1*8192, b_bk1, x2u, stats + 128);
  bnfin2_k<<<1,128,0,stream>>>(stats + 0, g1i, be1i, bnac + 0, g1u, be1u, bnac + 128);

  // ---- layer 2: materialize silu(x2), two per-relation spmms, gemms, output ----
  bnapply2_k<<<G8A,256,0,stream>>>(x2, bnac + 128, bnac + 0, NR2*DIM/8);
  spmm4_k<<<GS4,256,0,stream>>>(rs_go, col_all, x2, agg2, RN);
  spmm4_k<<<GS4,256,0,stream>>>(rs_bk, col_all, x2, agg2 + (size_t)RN*DIM, RN);
  gemm2_k<<<1024,256,0,stream>>>(agg2, x2i, wpack + 2*8192, b_go2, h2i, stats + 256);
  gemm2_k<<<1024,256,0,stream>>>(agg2 + (size_t)RN*DIM, x2u, wpack + 3*8192, b_bk2, h2u, stats + 384);
  bnfin2_k<<<1,128,0,stream>>>(stats + 256, g2i, be2i, bnac + 256, g2u, be2u, bnac + 384);
  bnout2_k<<<G8A,256,0,stream>>>(h2u, h2i, bnac + 384, bnac + 256, d_out, flags, NR2*DIM/8);
}

// Round 12
// 386.263 us; speedup vs baseline: 1.5736x; 1.1600x over previous
//
#include <hip/hip_runtime.h>
#include <cstdint>
#include <cstddef>

#define RN 200000   // nodes per side (NU == NI)
#define NR2 400000  // both sides
#define DIM 64
#define NE 1000000  // edges per relation
#define NB_PR 391   // buckets per relation (512 rows each)
#define NBB 782     // total buckets (go: 0..390, back: 391..781)
#define ET 4096     // edges per sort block
#define NBLK 489    // ceil(2*NE / ET)
#define NBLKP 512   // padded row length of C/Rloc (bucket-major)

typedef __attribute__((ext_vector_type(8))) short short8v;   // 8 x bf16 (4 VGPR)
typedef __attribute__((ext_vector_type(4))) float f32x4;
typedef __attribute__((ext_vector_type(8))) unsigned short us8;
typedef __attribute__((ext_vector_type(2))) unsigned int uint2v;

struct Ptrs16 { const void* p[16]; };

struct GemmCfg {
  const unsigned short* Agg;   // may alias Hout (in-place) -> no __restrict
  const unsigned short* Xd;
  const unsigned short* Wp;
  const float* bias;
  unsigned short* Hout;
  float* stats;
};

__device__ __forceinline__ float bf2f(unsigned short u){
  unsigned int x = ((unsigned int)u) << 16;
  return __builtin_bit_cast(float, x);
}
__device__ __forceinline__ unsigned short f2bf(float f){
  unsigned int x = __builtin_bit_cast(unsigned int, f);
  unsigned int r = x + 0x7fffu + ((x >> 16) & 1u);   // RNE
  return (unsigned short)(r >> 16);
}

// ---- dtype sniff + small-param convert + stats zero (single block) ----
__global__ __launch_bounds__(256) void detect2_k(const unsigned short* emb,
                                                 const unsigned int* esrc,
                                                 int* flags, Ptrs16 ps,
                                                 float* params, float* stats){
  __shared__ int cnt0, cnt1, sf0;
  int t = threadIdx.x;
  if (t == 0){ cnt0 = 0; cnt1 = 0; }
  __syncthreads();
  int c0 = 0, c1 = 0;
  #pragma unroll
  for (int s = 0; s < 4; ++s){
    int i = (t*4 + s) * 14;
    float af = fabsf(bf2f(emb[i]));
    if (af > 0.0009765625f && af < 32.0f) c0++;
    int e = t*4 + s;
    if (esrc[2*e + 1] != 0u) c1++;
  }
  atomicAdd(&cnt0, c0); atomicAdd(&cnt1, c1);
  __syncthreads();
  if (t == 0){
    int f0 = (cnt0 > 512) ? 1 : 0;
    int f1 = (cnt1 < 512) ? 1 : 0;
    flags[0] = f0; flags[1] = f1; sf0 = f0;
  }
  __syncthreads();
  int f0 = sf0;
  const int aidx[12] = {1,3,5,7,8,9,10,11,12,13,14,15};
  const int aoff[12] = {12288,24640,36992,49344,49408,49472,49536,49600,49664,49728,49792,49856};
  for (int base = t; base < 768; base += 256){
    int a = base >> 6, j = base & 63;
    const void* p = ps.p[aidx[a]];
    params[aoff[a] + j] = f0 ? bf2f(((const unsigned short*)p)[j]) : ((const float*)p)[j];
  }
  for (int z = t; z < 512; z += 256) stats[z] = 0.0f;
}

// ---- prepack the 4 weight matrices (raw inputs) into MFMA fragment order ----
__global__ __launch_bounds__(256) void prepack_k(Ptrs16 ps, const int* flags,
                                                 unsigned short* __restrict__ wpack){
  int i = blockIdx.x*256 + threadIdx.x;
  if (i >= 4*8192) return;
  int m = i >> 13, f = i & 8191;
  int r   = f & 7;
  int c16 = (f >> 3) & 15;
  int kg  = (f >> 7) & 3;
  int c   = (f >> 9) & 3;
  int t2  = (f >> 11) & 1;
  int s   = (f >> 12) & 1;
  int k = s*64 + t2*32 + kg*8 + r;
  int j = k*DIM + c*16 + c16;
  const void* wp = ps.p[m*2];          // W_go1, W_back1, W_go2, W_back2
  float v = flags[0] ? bf2f(((const unsigned short*)wp)[j]) : ((const float*)wp)[j];
  wpack[i] = f2bf(v);
}

// ---- canonicalize both embeddings into union bf16 buffer x1 (users, then items) ----
__global__ __launch_bounds__(256) void conv_emb2_k(const void* uin, const void* iin,
                                                   unsigned short* out,
                                                   const int* flags, int n8){
  int i = blockIdx.x*256 + threadIdx.x;
  if (i >= n8) return;
  int item = (i >= RN*8);
  const void* in = item ? iin : uin;
  int li = item ? i - RN*8 : i;
  us8 o;
  if (flags[0]){
    o = ((const us8*)in)[li];
  } else {
    const float* f = (const float*)in + (size_t)li*8;
    #pragma unroll
    for (int r = 0; r < 8; ++r) o[r] = f2bf(f[r]);
  }
  ((us8*)out)[i] = o;
}

// ==== CSR build: single-read merged histogram + scatter (validated R11) ====
__global__ __launch_bounds__(256) void pass12_k(const unsigned int* go_src, const unsigned int* go_dst,
                                                const unsigned int* back_src, const unsigned int* back_dst,
                                                int* __restrict__ C, int* __restrict__ Rloc,
                                                unsigned int* __restrict__ slab, const int* flags){
  __shared__ unsigned int spk[ET];      // 16KB: src | row_in_bucket<<18
  __shared__ unsigned short sbk[ET];    // 8KB: bucket id (0xFFFF = invalid)
  __shared__ int h[1024];               // histogram -> cursors
  __shared__ int ps[256];
  int blk = blockIdx.x, t = threadIdx.x;
  #pragma unroll
  for (int q = 0; q < 4; ++q) h[t + q*256] = 0;
  __syncthreads();
  int i64 = flags[1];
  int e0 = blk*ET;
  #pragma unroll
  for (int j = 0; j < 16; ++j){
    int e = e0 + j*256 + t;
    int li = j*256 + t;
    if (e < 2*NE){
      int rel = e >= NE;
      int ei = rel ? e - NE : e;
      const unsigned int* pd = rel ? back_dst : go_dst;
      const unsigned int* psr = rel ? back_src : go_src;
      int d  = i64 ? (int)pd[2*ei]  : (int)pd[ei];
      int sc = i64 ? (int)psr[2*ei] : (int)psr[ei];
      int b = (rel ? NB_PR : 0) + (d >> 9);
      spk[li] = (unsigned)sc | ((unsigned)(d & 511) << 18);
      sbk[li] = (unsigned short)b;
      atomicAdd(&h[b], 1);
    } else {
      sbk[li] = 0xFFFFu;
    }
  }
  __syncthreads();
  int c4[4], p4[4]; int s = 0;
  #pragma unroll
  for (int q = 0; q < 4; ++q){ c4[q] = h[t*4 + q]; p4[q] = s; s += c4[q]; }
  ps[t] = s;
  __syncthreads();
  for (int o = 1; o < 256; o <<= 1){
    int x = (t >= o) ? ps[t-o] : 0;
    __syncthreads();
    ps[t] += x;
    __syncthreads();
  }
  int base = (t > 0) ? ps[t-1] : 0;
  #pragma unroll
  for (int q = 0; q < 4; ++q){
    int b = t*4 + q;
    if (b < NBB){
      C[b*NBLKP + blk]    = c4[q];
      Rloc[b*NBLKP + blk] = base + p4[q];
    }
  }
  __syncthreads();                       // scan reads done; reuse h as cursors
  #pragma unroll
  for (int q = 0; q < 4; ++q){
    int b = t*4 + q;
    h[b] = base + p4[q];
  }
  __syncthreads();
  #pragma unroll
  for (int j = 0; j < 16; ++j){
    int li = j*256 + t;
    unsigned short b = sbk[li];
    if (b != 0xFFFFu){
      int pos = atomicAdd(&h[b], 1);
      slab[(size_t)blk*ET + pos] = spk[li];
    }
  }
}

__global__ __launch_bounds__(256) void sizes_k(const int* __restrict__ C, int* __restrict__ S){
  int w = blockIdx.x*4 + (threadIdx.x >> 6);
  int lane = threadIdx.x & 63;
  if (w >= NBB) return;
  int sum = 0;
  for (int k = lane; k < NBLK; k += 64) sum += C[w*NBLKP + k];
  #pragma unroll
  for (int o = 32; o > 0; o >>= 1) sum += __shfl_down(sum, o, 64);
  if (lane == 0) S[w] = sum;
}

__global__ __launch_bounds__(1024) void scanS_k(const int* __restrict__ S, int* __restrict__ s0,
                                                int* __restrict__ rs){
  __shared__ int sh[1024];
  int t = threadIdx.x;
  int v = (t < NBB) ? S[t] : 0;
  sh[t] = v;
  __syncthreads();
  for (int o = 1; o < 1024; o <<= 1){
    int x = (t >= o) ? sh[t-o] : 0;
    __syncthreads();
    sh[t] += x;
    __syncthreads();
  }
  if (t < NBB) s0[t] = sh[t] - v;
  if (t == NBB-1){ s0[NBB] = sh[t]; rs[NR2] = 2*NE; }
}

// ---- R12: per-RUN iteration (no binary search). Thread t owns run t. ----
// col written in UNION space (+RN for back-relation sources = items)
__global__ __launch_bounds__(512) void buildCSR3_k(const int* __restrict__ C,
                                                   const int* __restrict__ Rloc,
                                                   const int* __restrict__ s0g,
                                                   const unsigned int* __restrict__ slab,
                                                   int* __restrict__ rs, int* __restrict__ col){
  __shared__ int lcnt[512], lsc[512], lcur[512];
  int b = blockIdx.x, t = threadIdx.x;
  int cnt = 0, rst = 0;
  if (t < NBLK){ cnt = C[b*NBLKP + t]; rst = Rloc[b*NBLKP + t]; }
  lcnt[t] = 0;
  __syncthreads();
  const unsigned int* sl = slab + (size_t)t*ET + rst;   // only touched when cnt>0
  for (int k = 0; k < cnt; ++k){
    unsigned int q = sl[k];
    atomicAdd(&lcnt[q >> 18], 1);
  }
  __syncthreads();
  int rv = lcnt[t];
  lsc[t] = rv;
  __syncthreads();
  for (int o = 1; o < 512; o <<= 1){
    int x = (t >= o) ? lsc[t-o] : 0;
    __syncthreads();
    lsc[t] += x;
    __syncthreads();
  }
  int s0b = s0g[b];
  int d0 = (b < NB_PR) ? b*512 : RN + (b - NB_PR)*512;
  int relEnd = (b < NB_PR) ? RN : NR2;
  int rows = relEnd - d0; if (rows > 512) rows = 512;
  int srcoff = (b < NB_PR) ? 0 : RN;
  int start = lsc[t] - rv;
  lcur[t] = start;
  if (t < rows) rs[d0 + t] = s0b + start;
  __syncthreads();
  for (int k = 0; k < cnt; ++k){
    unsigned int q = sl[k];
    int p = atomicAdd(&lcur[q >> 18], 1);
    col[s0b + p] = (int)(q & 0x3FFFFu) + srcoff;
  }
}

// ---- SpMM R12: union rows, quarter-wave per dst row, dual output base.
// 16 lanes x 8 B per row, 4 rows/wave, 16-deep batches. ----
__global__ __launch_bounds__(256) void spmmU_k(const int* __restrict__ rs, const int* __restrict__ col,
                                               const unsigned short* __restrict__ Xg,
                                               unsigned short* outA, unsigned short* outB){
  int wv = (int)((blockIdx.x*256 + threadIdx.x) >> 6);
  int lane = threadIdx.x & 63;
  int hl = lane & 15;
  int row = wv*4 + (lane >> 4);        // grid exact: NR2/16 blocks
  int b = rs[row], e = rs[row+1];      // uniform within quarter (broadcast loads)
  int deg = e - b;
  int dq0 = __shfl(deg, 0), dq1 = __shfl(deg, 16);
  int dq2 = __shfl(deg, 32), dq3 = __shfl(deg, 48);
  int md = max(max(dq0, dq1), max(dq2, dq3));   // wave-uniform trip bound
  float a0 = 0, a1 = 0, a2 = 0, a3 = 0;
  for (int i = 0; i < md; i += 16){
    int idx[16];
    #pragma unroll
    for (int j = 0; j < 16; ++j){
      int o = i + j;
      int cid = b + ((o < deg) ? o : 0);
      int ix = col[cid];
      idx[j] = ((unsigned)ix < (unsigned)NR2) ? ix : 0;   // safety clamp
    }
    uint2v v[16];
    #pragma unroll
    for (int j = 0; j < 16; ++j)
      v[j] = *(const uint2v*)((const char*)Xg + (((size_t)(unsigned)idx[j]) << 7) + (hl << 3));
    #pragma unroll
    for (int j = 0; j < 16; ++j){
      if (i + j < deg){
        a0 += bf2f((unsigned short)(v[j].x & 0xFFFFu));
        a1 += bf2f((unsigned short)(v[j].x >> 16));
        a2 += bf2f((unsigned short)(v[j].y & 0xFFFFu));
        a3 += bf2f((unsigned short)(v[j].y >> 16));
      }
    }
  }
  float nrm = deg > 0 ? rsqrtf((float)deg) : 1.0f;
  uint2v pv;
  pv.x = (unsigned)f2bf(a0*nrm) | ((unsigned)f2bf(a1*nrm) << 16);
  pv.y = (unsigned)f2bf(a2*nrm) | ((unsigned)f2bf(a3*nrm) << 16);
  unsigned short* ob = (row < RN) ? (outA + ((size_t)row << 6))
                                  : (outB + ((size_t)(row - RN) << 6));
  __builtin_nontemporal_store(pv, (uint2v*)ob + hl);
}

// ---- merged GEMM: blocks [0,half) run cfg A, [half,2*half) run cfg B.
// H = Xd@W[0:64] + Agg@W[64:128] + b; prepacked B frags; fused BN stats.
// Agg may alias Hout (in-place back-relation): loads precede stores per tile. ----
__global__ __launch_bounds__(256) void gemm2m_k(GemmCfg cA, GemmCfg cB){
  __shared__ float ls[128];
  for (int t0 = threadIdx.x; t0 < 128; t0 += 256) ls[t0] = 0.0f;
  __syncthreads();
  int half = (int)(gridDim.x >> 1);
  bool sec = ((int)blockIdx.x >= half);
  const unsigned short* Agg = sec ? cB.Agg : cA.Agg;
  const unsigned short* Xd  = sec ? cB.Xd  : cA.Xd;
  const unsigned short* Wp  = sec ? cB.Wp  : cA.Wp;
  const float* bias         = sec ? cB.bias : cA.bias;
  unsigned short* Hout      = sec ? cB.Hout : cA.Hout;
  float* stats              = sec ? cB.stats : cA.stats;
  int lb = sec ? (int)blockIdx.x - half : (int)blockIdx.x;
  int lane = threadIdx.x & 63;
  int gw = lb*4 + (int)(threadIdx.x >> 6);
  int nw = half*4;
  int c16 = lane & 15, kg = lane >> 4;

  short8v Bf[2][2][4];
  #pragma unroll
  for (int s = 0; s < 2; ++s)
    #pragma unroll
    for (int t2 = 0; t2 < 2; ++t2)
      #pragma unroll
      for (int c = 0; c < 4; ++c)
        Bf[s][t2][c] = ((const short8v*)Wp)[(((s*2 + t2)*4 + c)*4 + kg)*16 + c16];
  float bc[4];
  #pragma unroll
  for (int c = 0; c < 4; ++c) bc[c] = bias[c*16 + c16];

  float ssum[4] = {0,0,0,0}, ssq[4] = {0,0,0,0};
  const int ntile = RN/16;
  for (int tile = gw; tile < ntile; tile += nw){
    int r0 = tile*16;
    int ar = r0 + c16;
    short8v A00 = ((const short8v*)Xd)[ar*8 + kg];
    short8v A01 = ((const short8v*)Xd)[ar*8 + 4 + kg];
    short8v A10 = ((const short8v*)Agg)[ar*8 + kg];
    short8v A11 = ((const short8v*)Agg)[ar*8 + 4 + kg];
    f32x4 acc4[4];
    #pragma unroll
    for (int c = 0; c < 4; ++c){ f32x4 z = {bc[c],bc[c],bc[c],bc[c]}; acc4[c] = z; }
    #pragma unroll
    for (int c = 0; c < 4; ++c){
      acc4[c] = __builtin_amdgcn_mfma_f32_16x16x32_bf16(A00, Bf[0][0][c], acc4[c], 0, 0, 0);
      acc4[c] = __builtin_amdgcn_mfma_f32_16x16x32_bf16(A01, Bf[0][1][c], acc4[c], 0, 0, 0);
      acc4[c] = __builtin_amdgcn_mfma_f32_16x16x32_bf16(A10, Bf[1][0][c], acc4[c], 0, 0, 0);
      acc4[c] = __builtin_amdgcn_mfma_f32_16x16x32_bf16(A11, Bf[1][1][c], acc4[c], 0, 0, 0);
    }
    int orow = r0 + kg*4;   // C layout: col = lane&15, row = (lane>>4)*4 + reg [m89]
    #pragma unroll
    for (int c = 0; c < 4; ++c)
      #pragma unroll
      for (int r = 0; r < 4; ++r){
        float v = acc4[c][r];
        ssum[c] += v; ssq[c] += v*v;
        __builtin_nontemporal_store(f2bf(v), &Hout[(size_t)(orow + r)*DIM + c*16 + c16]);
      }
  }
  #pragma unroll
  for (int c = 0; c < 4; ++c){
    atomicAdd(&ls[c*16 + c16], ssum[c]);
    atomicAdd(&ls[64 + c*16 + c16], ssq[c]);
  }
  __syncthreads();
  for (int t0 = threadIdx.x; t0 < 128; t0 += 256) atomicAdd(&stats[t0], ls[t0]);
}

// ---- BN finalize for both halves of a layer ----
__global__ __launch_bounds__(128) void bnfin2_k(const float* stats,
                                                const float* gI, const float* beI, float* acI,
                                                const float* gU, const float* beU, float* acU){
  int t = threadIdx.x, j = t & 63;
  const float* st = (t < 64) ? stats : stats + 128;
  float mu  = st[j]    * (1.0f/RN);
  float var = st[64+j] * (1.0f/RN) - mu*mu;
  float inv = rsqrtf(var + 1e-5f);
  if (t < 64){ float a = gI[j]*inv; acI[j] = a; acI[64+j] = beI[j] - mu*a; }
  else       { float a = gU[j]*inv; acU[j] = a; acU[64+j] = beU[j] - mu*a; }
}

// ---- BN + SiLU in-place over the union buffer (users half then items half) ----
__global__ __launch_bounds__(256) void bnapply2_k(unsigned short* H,
                                                  const float* __restrict__ acU,
                                                  const float* __restrict__ acI, int n8){
  int i = blockIdx.x*256 + threadIdx.x;
  if (i >= n8) return;
  const float* ac = (i < RN*8) ? acU : acI;
  us8 v = ((us8*)H)[i];
  int cb = (i*8) & 63;
  #pragma unroll
  for (int r = 0; r < 8; ++r){
    float x = bf2f(v[r]);
    float y = ac[cb+r]*x + ac[64+cb+r];
    float o = y / (1.0f + expf(-y));
    v[r] = f2bf(o);
  }
  ((us8*)H)[i] = v;
}

// ---- BN + SiLU to d_out; user rows from Hu, item rows from Hi ----
__global__ __launch_bounds__(256) void bnout2_k(const unsigned short* __restrict__ Hu,
                                                const unsigned short* __restrict__ Hi,
                                                const float* __restrict__ acU,
                                                const float* __restrict__ acI,
                                                void* out, const int* __restrict__ flags, int n8){
  int i = blockIdx.x*256 + threadIdx.x;
  if (i >= n8) return;
  int item = (i >= RN*8);
  const float* ac = item ? acI : acU;
  us8 v = item ? ((const us8*)Hi)[i - RN*8] : ((const us8*)Hu)[i];
  int cb = (i*8) & 63;
  float o[8];
  #pragma unroll
  for (int r = 0; r < 8; ++r){
    float x = bf2f(v[r]);
    float y = ac[cb+r]*x + ac[64+cb+r];
    o[r] = y / (1.0f + expf(-y));
  }
  if (flags[0]){
    unsigned short* ob = (unsigned short*)out + (size_t)i*8;
    us8 wv;
    #pragma unroll
    for (int r = 0; r < 8; ++r) wv[r] = f2bf(o[r]);
    __builtin_nontemporal_store(wv, (us8*)ob);
  } else {
    float* ob = (float*)out + (size_t)i*8;
    f32x4 w0 = {o[0],o[1],o[2],o[3]}, w1 = {o[4],o[5],o[6],o[7]};
    __builtin_nontemporal_store(w0, (f32x4*)ob);
    __builtin_nontemporal_store(w1, (f32x4*)ob + 1);
  }
}

extern "C" void kernel_launch(void* const* d_in, const int* in_sizes, int n_in,
                              void* d_out, int out_size, void* d_ws, size_t ws_size,
                              hipStream_t stream){
  (void)in_sizes; (void)n_in; (void)out_size;
  const void* user_emb = d_in[0];
  const void* item_emb = d_in[1];
  const void* go_src   = d_in[18];
  const void* go_dst   = d_in[19];
  const void* back_src = d_in[20];
  const void* back_dst = d_in[21];

  char* ws = (char*)d_ws;
  size_t off = 0;
  auto alloc = [&](size_t bytes) -> void* {
    void* p = ws + off;
    off += (bytes + 255) & ~((size_t)255);
    return p;
  };
  int*   flags  = (int*)  alloc(64);
  float* params = (float*)alloc((size_t)49920*4);
  unsigned short* wpack = (unsigned short*)alloc((size_t)4*8192*2);
  float* bnac   = (float*)alloc(512*4);
  float* stats  = (float*)alloc(512*4);
  int*   Cmat   = (int*)  alloc((size_t)NBB*NBLKP*4);
  int*   Rloc   = (int*)  alloc((size_t)NBB*NBLKP*4);
  int*   Sbuf   = (int*)  alloc(1024*4);
  int*   s0g    = (int*)  alloc(1024*4);
  int*   rs_all = (int*)  alloc((size_t)(NR2+1)*4);
  int*   col_all= (int*)  alloc(((size_t)2*NE + 64)*4);              // +64 pad: deg-0 tail reads
  unsigned short* x1   = (unsigned short*)alloc((size_t)NR2*DIM*2);  // embeddings -> layer-2 agg/out
  unsigned short* x2   = (unsigned short*)alloc((size_t)NR2*DIM*2);  // slab -> layer-1 out (silu'd)
  unsigned short* agg1 = (unsigned short*)alloc((size_t)RN*DIM*2);   // go agg -> layer-2 item out
  if (off > ws_size) return;  // visible as absmax == 5.8125

  unsigned int* slab = (unsigned int*)x2;   // 8MB alias; dead after buildCSR3

  unsigned short* x1u = x1;
  unsigned short* x1i = x1 + (size_t)RN*DIM;
  unsigned short* x2u = x2;
  unsigned short* x2i = x2 + (size_t)RN*DIM;

  const int G8A = (NR2*DIM/8)/256;          // 12500
  const int GSU = NR2/16;                   // 25000 blocks: union spmm, 4 rows/wave

  float* b_go1 = params + 12288;
  float* b_bk1 = params + 24640;
  float* b_go2 = params + 36992;
  float* b_bk2 = params + 49344;
  float* g1u = params + 49408; float* be1u = params + 49472;
  float* g1i = params + 49536; float* be1i = params + 49600;
  float* g2u = params + 49664; float* be2u = params + 49728;
  float* g2i = params + 49792; float* be2i = params + 49856;

  Ptrs16 ps;
  for (int i = 0; i < 16; ++i) ps.p[i] = d_in[2+i];

  detect2_k<<<1,256,0,stream>>>((const unsigned short*)user_emb, (const unsigned int*)go_src,
                                flags, ps, params, stats);
  prepack_k<<<128,256,0,stream>>>(ps, flags, wpack);
  conv_emb2_k<<<G8A,256,0,stream>>>(user_emb, item_emb, x1, flags, NR2*DIM/8);

  // ---- CSR build ----
  pass12_k<<<NBLK,256,0,stream>>>((const unsigned int*)go_src, (const unsigned int*)go_dst,
                                  (const unsigned int*)back_src, (const unsigned int*)back_dst,
                                  Cmat, Rloc, slab, flags);
  sizes_k<<<(NBB+3)/4,256,0,stream>>>(Cmat, Sbuf);
  scanS_k<<<1,1024,0,stream>>>(Sbuf, s0g, rs_all);
  buildCSR3_k<<<NBB,512,0,stream>>>(Cmat, Rloc, s0g, slab, rs_all, col_all);

  // ---- layer 1: one union spmm (go rows -> agg1, back rows -> x2u scratch),
  //      one merged gemm (go: agg1+x1i -> x2i; back: x2u+x1u -> x2u in-place) ----
  spmmU_k<<<GSU,256,0,stream>>>(rs_all, col_all, x1, agg1, x2u);
  {
    GemmCfg go1{agg1, x1i, wpack + 0*8192, b_go1, x2i, stats + 0};
    GemmCfg bk1{x2u,  x1u, wpack + 1*8192, b_bk1, x2u, stats + 128};
    gemm2m_k<<<1024,256,0,stream>>>(go1, bk1);
  }
  bnfin2_k<<<1,128,0,stream>>>(stats + 0, g1i, be1i, bnac + 0, g1u, be1u, bnac + 128);
  bnapply2_k<<<G8A,256,0,stream>>>(x2, bnac + 128, bnac + 0, NR2*DIM/8);

  // ---- layer 2: union spmm from silu'd x2 -> agg2 = x1 (union),
  //      merged gemm (go: x1lo+x2i -> agg1; back: x1hi+x2u -> x1hi in-place) ----
  spmmU_k<<<GSU,256,0,stream>>>(rs_all, col_all, x2, x1u, x1i);
  {
    GemmCfg go2{x1u, x2i, wpack + 2*8192, b_go2, agg1, stats + 256};
    GemmCfg bk2{x1i, x2u, wpack + 3*8192, b_bk2, x1i,  stats + 384};
    gemm2m_k<<<1024,256,0,stream>>>(go2, bk2);
  }
  bnfin2_k<<<1,128,0,stream>>>(stats + 256, g2i, be2i, bnac + 256, g2u, be2u, bnac + 384);
  bnout2_k<<<G8A,256,0,stream>>>(x1i, agg1, bnac + 384, bnac + 256, d_out, flags, NR2*DIM/8);
}

// Round 13
// 354.863 us; speedup vs baseline: 1.7129x; 1.0885x over previous
//
#include <hip/hip_runtime.h>
#include <cstdint>
#include <cstddef>

#define RN 200000   // nodes per side (NU == NI)
#define NR2 400000  // both sides
#define DIM 64
#define NE 1000000  // edges per relation
#define NB_PR 391   // buckets per relation (512 rows each)
#define NBB 782     // total buckets (go: 0..390, back: 391..781)
#define ET 4096     // edges per sort block
#define NBLK 489    // ceil(2*NE / ET)
#define NBLKP 512   // padded row length of C/Rloc (bucket-major)

typedef __attribute__((ext_vector_type(8))) short short8v;   // 8 x bf16 (4 VGPR)
typedef __attribute__((ext_vector_type(4))) float f32x4;
typedef __attribute__((ext_vector_type(8))) unsigned short us8;
typedef __attribute__((ext_vector_type(2))) unsigned int uint2v;

struct Ptrs16 { const void* p[16]; };

struct GemmCfg {
  const unsigned short* Agg;   // may alias Hout (in-place) -> no __restrict
  const unsigned short* Xd;
  const unsigned short* Wp;
  const float* bias;
  unsigned short* Hout;
  float* stats;
};

__device__ __forceinline__ float bf2f(unsigned short u){
  unsigned int x = ((unsigned int)u) << 16;
  return __builtin_bit_cast(float, x);
}
__device__ __forceinline__ unsigned short f2bf(float f){
  unsigned int x = __builtin_bit_cast(unsigned int, f);
  unsigned int r = x + 0x7fffu + ((x >> 16) & 1u);   // RNE
  return (unsigned short)(r >> 16);
}

// ---- dtype sniff + small-param convert + stats zero (single block) ----
__global__ __launch_bounds__(256) void detect2_k(const unsigned short* emb,
                                                 const unsigned int* esrc,
                                                 int* flags, Ptrs16 ps,
                                                 float* params, float* stats){
  __shared__ int cnt0, cnt1, sf0;
  int t = threadIdx.x;
  if (t == 0){ cnt0 = 0; cnt1 = 0; }
  __syncthreads();
  int c0 = 0, c1 = 0;
  #pragma unroll
  for (int s = 0; s < 4; ++s){
    int i = (t*4 + s) * 14;
    float af = fabsf(bf2f(emb[i]));
    if (af > 0.0009765625f && af < 32.0f) c0++;
    int e = t*4 + s;
    if (esrc[2*e + 1] != 0u) c1++;
  }
  atomicAdd(&cnt0, c0); atomicAdd(&cnt1, c1);
  __syncthreads();
  if (t == 0){
    int f0 = (cnt0 > 512) ? 1 : 0;
    int f1 = (cnt1 < 512) ? 1 : 0;
    flags[0] = f0; flags[1] = f1; sf0 = f0;
  }
  __syncthreads();
  int f0 = sf0;
  const int aidx[12] = {1,3,5,7,8,9,10,11,12,13,14,15};
  const int aoff[12] = {12288,24640,36992,49344,49408,49472,49536,49600,49664,49728,49792,49856};
  for (int base = t; base < 768; base += 256){
    int a = base >> 6, j = base & 63;
    const void* p = ps.p[aidx[a]];
    params[aoff[a] + j] = f0 ? bf2f(((const unsigned short*)p)[j]) : ((const float*)p)[j];
  }
  for (int z = t; z < 512; z += 256) stats[z] = 0.0f;
}

// ---- fused: blocks [0,128) prepack the 4 weight mats into MFMA frag order;
//      blocks [128, 128+n8/256) canonicalize embeddings into union bf16 x1 ----
__global__ __launch_bounds__(256) void convpp_k(const void* uin, const void* iin,
                                                unsigned short* __restrict__ out,
                                                Ptrs16 ps, unsigned short* __restrict__ wpack,
                                                const int* flags, int n8){
  int bid = blockIdx.x;
  if (bid < 128){
    int i = bid*256 + threadIdx.x;
    int m = i >> 13, f = i & 8191;
    int r   = f & 7;
    int c16 = (f >> 3) & 15;
    int kg  = (f >> 7) & 3;
    int c   = (f >> 9) & 3;
    int t2  = (f >> 11) & 1;
    int s   = (f >> 12) & 1;
    int k = s*64 + t2*32 + kg*8 + r;
    int j = k*DIM + c*16 + c16;
    const void* wp = ps.p[m*2];        // W_go1, W_back1, W_go2, W_back2
    float v = flags[0] ? bf2f(((const unsigned short*)wp)[j]) : ((const float*)wp)[j];
    wpack[i] = f2bf(v);
    return;
  }
  int i = (bid - 128)*256 + threadIdx.x;
  if (i >= n8) return;
  int item = (i >= RN*8);
  const void* in = item ? iin : uin;
  int li = item ? i - RN*8 : i;
  us8 o;
  if (flags[0]){
    o = ((const us8*)in)[li];
  } else {
    const float* f = (const float*)in + (size_t)li*8;
    #pragma unroll
    for (int r = 0; r < 8; ++r) o[r] = f2bf(f[r]);
  }
  ((us8*)out)[i] = o;
}

// ==== CSR build: single-read merged histogram + scatter (validated R11) ====
__global__ __launch_bounds__(256) void pass12_k(const unsigned int* go_src, const unsigned int* go_dst,
                                                const unsigned int* back_src, const unsigned int* back_dst,
                                                int* __restrict__ C, int* __restrict__ Rloc,
                                                unsigned int* __restrict__ slab, const int* flags){
  __shared__ unsigned int spk[ET];      // 16KB: src | row_in_bucket<<18
  __shared__ unsigned short sbk[ET];    // 8KB: bucket id (0xFFFF = invalid)
  __shared__ int h[1024];               // histogram -> cursors
  __shared__ int ps[256];
  int blk = blockIdx.x, t = threadIdx.x;
  #pragma unroll
  for (int q = 0; q < 4; ++q) h[t + q*256] = 0;
  __syncthreads();
  int i64 = flags[1];
  int e0 = blk*ET;
  #pragma unroll
  for (int j = 0; j < 16; ++j){
    int e = e0 + j*256 + t;
    int li = j*256 + t;
    if (e < 2*NE){
      int rel = e >= NE;
      int ei = rel ? e - NE : e;
      const unsigned int* pd = rel ? back_dst : go_dst;
      const unsigned int* psr = rel ? back_src : go_src;
      int d  = i64 ? (int)pd[2*ei]  : (int)pd[ei];
      int sc = i64 ? (int)psr[2*ei] : (int)psr[ei];
      int b = (rel ? NB_PR : 0) + (d >> 9);
      spk[li] = (unsigned)sc | ((unsigned)(d & 511) << 18);
      sbk[li] = (unsigned short)b;
      atomicAdd(&h[b], 1);
    } else {
      sbk[li] = 0xFFFFu;
    }
  }
  __syncthreads();
  int c4[4], p4[4]; int s = 0;
  #pragma unroll
  for (int q = 0; q < 4; ++q){ c4[q] = h[t*4 + q]; p4[q] = s; s += c4[q]; }
  ps[t] = s;
  __syncthreads();
  for (int o = 1; o < 256; o <<= 1){
    int x = (t >= o) ? ps[t-o] : 0;
    __syncthreads();
    ps[t] += x;
    __syncthreads();
  }
  int base = (t > 0) ? ps[t-1] : 0;
  #pragma unroll
  for (int q = 0; q < 4; ++q){
    int b = t*4 + q;
    if (b < NBB){
      C[b*NBLKP + blk]    = c4[q];
      Rloc[b*NBLKP + blk] = base + p4[q];
    }
  }
  __syncthreads();                       // scan reads done; reuse h as cursors
  #pragma unroll
  for (int q = 0; q < 4; ++q){
    int b = t*4 + q;
    h[b] = base + p4[q];
  }
  __syncthreads();
  #pragma unroll
  for (int j = 0; j < 16; ++j){
    int li = j*256 + t;
    unsigned short b = sbk[li];
    if (b != 0xFFFFu){
      int pos = atomicAdd(&h[b], 1);
      slab[(size_t)blk*ET + pos] = spk[li];
    }
  }
}

__global__ __launch_bounds__(256) void sizes_k(const int* __restrict__ C, int* __restrict__ S){
  int w = blockIdx.x*4 + (threadIdx.x >> 6);
  int lane = threadIdx.x & 63;
  if (w >= NBB) return;
  int sum = 0;
  for (int k = lane; k < NBLK; k += 64) sum += C[w*NBLKP + k];
  #pragma unroll
  for (int o = 32; o > 0; o >>= 1) sum += __shfl_down(sum, o, 64);
  if (lane == 0) S[w] = sum;
}

__global__ __launch_bounds__(1024) void scanS_k(const int* __restrict__ S, int* __restrict__ s0,
                                                int* __restrict__ rs){
  __shared__ int sh[1024];
  int t = threadIdx.x;
  int v = (t < NBB) ? S[t] : 0;
  sh[t] = v;
  __syncthreads();
  for (int o = 1; o < 1024; o <<= 1){
    int x = (t >= o) ? sh[t-o] : 0;
    __syncthreads();
    sh[t] += x;
    __syncthreads();
  }
  if (t < NBB) s0[t] = sh[t] - v;
  if (t == NBB-1){ s0[NBB] = sh[t]; rs[NR2] = 2*NE; }
}

// ---- per-RUN iteration (no binary search; validated R12). Thread t owns run t.
// col written in UNION space (+RN for back-relation sources = items) ----
__global__ __launch_bounds__(512) void buildCSR3_k(const int* __restrict__ C,
                                                   const int* __restrict__ Rloc,
                                                   const int* __restrict__ s0g,
                                                   const unsigned int* __restrict__ slab,
                                                   int* __restrict__ rs, int* __restrict__ col){
  __shared__ int lcnt[512], lsc[512], lcur[512];
  int b = blockIdx.x, t = threadIdx.x;
  int cnt = 0, rst = 0;
  if (t < NBLK){ cnt = C[b*NBLKP + t]; rst = Rloc[b*NBLKP + t]; }
  lcnt[t] = 0;
  __syncthreads();
  const unsigned int* sl = slab + (size_t)t*ET + rst;   // only touched when cnt>0
  for (int k = 0; k < cnt; ++k){
    unsigned int q = sl[k];
    atomicAdd(&lcnt[q >> 18], 1);
  }
  __syncthreads();
  int rv = lcnt[t];
  lsc[t] = rv;
  __syncthreads();
  for (int o = 1; o < 512; o <<= 1){
    int x = (t >= o) ? lsc[t-o] : 0;
    __syncthreads();
    lsc[t] += x;
    __syncthreads();
  }
  int s0b = s0g[b];
  int d0 = (b < NB_PR) ? b*512 : RN + (b - NB_PR)*512;
  int relEnd = (b < NB_PR) ? RN : NR2;
  int rows = relEnd - d0; if (rows > 512) rows = 512;
  int srcoff = (b < NB_PR) ? 0 : RN;
  int start = lsc[t] - rv;
  lcur[t] = start;
  if (t < rows) rs[d0 + t] = s0b + start;
  __syncthreads();
  for (int k = 0; k < cnt; ++k){
    unsigned int q = sl[k];
    int p = atomicAdd(&lcur[q >> 18], 1);
    col[s0b + p] = (int)(q & 0x3FFFFu) + srcoff;
  }
}

// ---- SpMM R13: union rows, quarter-wave per dst row, dual output base.
// col via lane-parallel load + shfl (1 VMEM inst / 16 slots); two-tier
// wave-uniform depth (md<=8 fast path kills clamp waste for avg deg ~5). ----
__global__ __launch_bounds__(256) void spmmU_k(const int* __restrict__ rs, const int* __restrict__ col,
                                               const unsigned short* __restrict__ Xg,
                                               unsigned short* outA, unsigned short* outB){
  int wv = (int)((blockIdx.x*256 + threadIdx.x) >> 6);
  int lane = threadIdx.x & 63;
  int hl = lane & 15;
  int qb = lane & 48;                  // quarter base lane
  int row = wv*4 + (lane >> 4);        // grid exact: NR2/16 blocks
  int b = rs[row], e = rs[row+1];      // uniform within quarter
  int deg = e - b;
  int dq0 = __shfl(deg, 0), dq1 = __shfl(deg, 16);
  int dq2 = __shfl(deg, 32), dq3 = __shfl(deg, 48);
  int md = max(max(dq0, dq1), max(dq2, dq3));   // wave-uniform trip bound
  float a0 = 0, a1 = 0, a2 = 0, a3 = 0;

  if (md <= 8){                         // wave-uniform fast path (avg md ~8.5)
    if (md > 0){
      int cv = col[b + ((hl < deg) ? hl : 0)];   // lane hl holds col[b+hl]
      uint2v v[8];
      #pragma unroll
      for (int j = 0; j < 8; ++j){
        int ix = __shfl(cv, qb + j, 64);
        ix = ((unsigned)ix < (unsigned)NR2) ? ix : 0;
        v[j] = *(const uint2v*)((const char*)Xg + (((size_t)(unsigned)ix) << 7) + (hl << 3));
      }
      #pragma unroll
      for (int j = 0; j < 8; ++j){
        if (j < deg){
          a0 += bf2f((unsigned short)(v[j].x & 0xFFFFu));
          a1 += bf2f((unsigned short)(v[j].x >> 16));
          a2 += bf2f((unsigned short)(v[j].y & 0xFFFFu));
          a3 += bf2f((unsigned short)(v[j].y >> 16));
        }
      }
    }
  } else {
    for (int i = 0; i < md; i += 16){
      int o = i + hl;
      int cv = col[b + ((o < deg) ? o : 0)];     // lane hl holds col[b+i+hl]
      uint2v v[16];
      #pragma unroll
      for (int j = 0; j < 16; ++j){
        int ix = __shfl(cv, qb + j, 64);
        ix = ((unsigned)ix < (unsigned)NR2) ? ix : 0;
        v[j] = *(const uint2v*)((const char*)Xg + (((size_t)(unsigned)ix) << 7) + (hl << 3));
      }
      #pragma unroll
      for (int j = 0; j < 16; ++j){
        if (i + j < deg){
          a0 += bf2f((unsigned short)(v[j].x & 0xFFFFu));
          a1 += bf2f((unsigned short)(v[j].x >> 16));
          a2 += bf2f((unsigned short)(v[j].y & 0xFFFFu));
          a3 += bf2f((unsigned short)(v[j].y >> 16));
        }
      }
    }
  }
  float nrm = deg > 0 ? rsqrtf((float)deg) : 1.0f;
  uint2v pv;
  pv.x = (unsigned)f2bf(a0*nrm) | ((unsigned)f2bf(a1*nrm) << 16);
  pv.y = (unsigned)f2bf(a2*nrm) | ((unsigned)f2bf(a3*nrm) << 16);
  unsigned short* ob = (row < RN) ? (outA + ((size_t)row << 6))
                                  : (outB + ((size_t)(row - RN) << 6));
  __builtin_nontemporal_store(pv, (uint2v*)ob + hl);
}

// ---- merged GEMM: blocks [0,half) run cfg A, [half,2*half) run cfg B.
// H = Xd@W[0:64] + Agg@W[64:128] + b; prepacked B frags; fused BN stats.
// Agg may alias Hout (in-place back-relation): loads precede stores per tile. ----
__global__ __launch_bounds__(256) void gemm2m_k(GemmCfg cA, GemmCfg cB){
  __shared__ float ls[128];
  for (int t0 = threadIdx.x; t0 < 128; t0 += 256) ls[t0] = 0.0f;
  __syncthreads();
  int half = (int)(gridDim.x >> 1);
  bool sec = ((int)blockIdx.x >= half);
  const unsigned short* Agg = sec ? cB.Agg : cA.Agg;
  const unsigned short* Xd  = sec ? cB.Xd  : cA.Xd;
  const unsigned short* Wp  = sec ? cB.Wp  : cA.Wp;
  const float* bias         = sec ? cB.bias : cA.bias;
  unsigned short* Hout      = sec ? cB.Hout : cA.Hout;
  float* stats              = sec ? cB.stats : cA.stats;
  int lb = sec ? (int)blockIdx.x - half : (int)blockIdx.x;
  int lane = threadIdx.x & 63;
  int gw = lb*4 + (int)(threadIdx.x >> 6);
  int nw = half*4;
  int c16 = lane & 15, kg = lane >> 4;

  short8v Bf[2][2][4];
  #pragma unroll
  for (int s = 0; s < 2; ++s)
    #pragma unroll
    for (int t2 = 0; t2 < 2; ++t2)
      #pragma unroll
      for (int c = 0; c < 4; ++c)
        Bf[s][t2][c] = ((const short8v*)Wp)[(((s*2 + t2)*4 + c)*4 + kg)*16 + c16];
  float bc[4];
  #pragma unroll
  for (int c = 0; c < 4; ++c) bc[c] = bias[c*16 + c16];

  float ssum[4] = {0,0,0,0}, ssq[4] = {0,0,0,0};
  const int ntile = RN/16;
  for (int tile = gw; tile < ntile; tile += nw){
    int r0 = tile*16;
    int ar = r0 + c16;
    short8v A00 = ((const short8v*)Xd)[ar*8 + kg];
    short8v A01 = ((const short8v*)Xd)[ar*8 + 4 + kg];
    short8v A10 = ((const short8v*)Agg)[ar*8 + kg];
    short8v A11 = ((const short8v*)Agg)[ar*8 + 4 + kg];
    f32x4 acc4[4];
    #pragma unroll
    for (int c = 0; c < 4; ++c){ f32x4 z = {bc[c],bc[c],bc[c],bc[c]}; acc4[c] = z; }
    #pragma unroll
    for (int c = 0; c < 4; ++c){
      acc4[c] = __builtin_amdgcn_mfma_f32_16x16x32_bf16(A00, Bf[0][0][c], acc4[c], 0, 0, 0);
      acc4[c] = __builtin_amdgcn_mfma_f32_16x16x32_bf16(A01, Bf[0][1][c], acc4[c], 0, 0, 0);
      acc4[c] = __builtin_amdgcn_mfma_f32_16x16x32_bf16(A10, Bf[1][0][c], acc4[c], 0, 0, 0);
      acc4[c] = __builtin_amdgcn_mfma_f32_16x16x32_bf16(A11, Bf[1][1][c], acc4[c], 0, 0, 0);
    }
    int orow = r0 + kg*4;   // C layout: col = lane&15, row = (lane>>4)*4 + reg [m89]
    #pragma unroll
    for (int c = 0; c < 4; ++c)
      #pragma unroll
      for (int r = 0; r < 4; ++r){
        float v = acc4[c][r];
        ssum[c] += v; ssq[c] += v*v;
        __builtin_nontemporal_store(f2bf(v), &Hout[(size_t)(orow + r)*DIM + c*16 + c16]);
      }
  }
  #pragma unroll
  for (int c = 0; c < 4; ++c){
    atomicAdd(&ls[c*16 + c16], ssum[c]);
    atomicAdd(&ls[64 + c*16 + c16], ssq[c]);
  }
  __syncthreads();
  for (int t0 = threadIdx.x; t0 < 128; t0 += 256) atomicAdd(&stats[t0], ls[t0]);
}

// ---- BN finalize for both halves of a layer ----
__global__ __launch_bounds__(128) void bnfin2_k(const float* stats,
                                                const float* gI, const float* beI, float* acI,
                                                const float* gU, const float* beU, float* acU){
  int t = threadIdx.x, j = t & 63;
  const float* st = (t < 64) ? stats : stats + 128;
  float mu  = st[j]    * (1.0f/RN);
  float var = st[64+j] * (1.0f/RN) - mu*mu;
  float inv = rsqrtf(var + 1e-5f);
  if (t < 64){ float a = gI[j]*inv; acI[j] = a; acI[64+j] = beI[j] - mu*a; }
  else       { float a = gU[j]*inv; acU[j] = a; acU[64+j] = beU[j] - mu*a; }
}

// ---- BN + SiLU in-place over the union buffer (users half then items half) ----
__global__ __launch_bounds__(256) void bnapply2_k(unsigned short* H,
                                                  const float* __restrict__ acU,
                                                  const float* __restrict__ acI, int n8){
  int i = blockIdx.x*256 + threadIdx.x;
  if (i >= n8) return;
  const float* ac = (i < RN*8) ? acU : acI;
  us8 v = ((us8*)H)[i];
  int cb = (i*8) & 63;
  #pragma unroll
  for (int r = 0; r < 8; ++r){
    float x = bf2f(v[r]);
    float y = ac[cb+r]*x + ac[64+cb+r];
    float o = y / (1.0f + expf(-y));
    v[r] = f2bf(o);
  }
  ((us8*)H)[i] = v;
}

// ---- BN + SiLU to d_out; user rows from Hu, item rows from Hi ----
__global__ __launch_bounds__(256) void bnout2_k(const unsigned short* __restrict__ Hu,
                                                const unsigned short* __restrict__ Hi,
                                                const float* __restrict__ acU,
                                                const float* __restrict__ acI,
                                                void* out, const int* __restrict__ flags, int n8){
  int i = blockIdx.x*256 + threadIdx.x;
  if (i >= n8) return;
  int item = (i >= RN*8);
  const float* ac = item ? acI : acU;
  us8 v = item ? ((const us8*)Hi)[i - RN*8] : ((const us8*)Hu)[i];
  int cb = (i*8) & 63;
  float o[8];
  #pragma unroll
  for (int r = 0; r < 8; ++r){
    float x = bf2f(v[r]);
    float y = ac[cb+r]*x + ac[64+cb+r];
    o[r] = y / (1.0f + expf(-y));
  }
  if (flags[0]){
    unsigned short* ob = (unsigned short*)out + (size_t)i*8;
    us8 wv;
    #pragma unroll
    for (int r = 0; r < 8; ++r) wv[r] = f2bf(o[r]);
    __builtin_nontemporal_store(wv, (us8*)ob);
  } else {
    float* ob = (float*)out + (size_t)i*8;
    f32x4 w0 = {o[0],o[1],o[2],o[3]}, w1 = {o[4],o[5],o[6],o[7]};
    __builtin_nontemporal_store(w0, (f32x4*)ob);
    __builtin_nontemporal_store(w1, (f32x4*)ob + 1);
  }
}

extern "C" void kernel_launch(void* const* d_in, const int* in_sizes, int n_in,
                              void* d_out, int out_size, void* d_ws, size_t ws_size,
                              hipStream_t stream){
  (void)in_sizes; (void)n_in; (void)out_size;
  const void* user_emb = d_in[0];
  const void* item_emb = d_in[1];
  const void* go_src   = d_in[18];
  const void* go_dst   = d_in[19];
  const void* back_src = d_in[20];
  const void* back_dst = d_in[21];

  char* ws = (char*)d_ws;
  size_t off = 0;
  auto alloc = [&](size_t bytes) -> void* {
    void* p = ws + off;
    off += (bytes + 255) & ~((size_t)255);
    return p;
  };
  int*   flags  = (int*)  alloc(64);
  float* params = (float*)alloc((size_t)49920*4);
  unsigned short* wpack = (unsigned short*)alloc((size_t)4*8192*2);
  float* bnac   = (float*)alloc(512*4);
  float* stats  = (float*)alloc(512*4);
  int*   Cmat   = (int*)  alloc((size_t)NBB*NBLKP*4);
  int*   Rloc   = (int*)  alloc((size_t)NBB*NBLKP*4);
  int*   Sbuf   = (int*)  alloc(1024*4);
  int*   s0g    = (int*)  alloc(1024*4);
  int*   rs_all = (int*)  alloc((size_t)(NR2+1)*4);
  int*   col_all= (int*)  alloc(((size_t)2*NE + 64)*4);              // +64 pad: deg-0 tail reads
  unsigned short* x1   = (unsigned short*)alloc((size_t)NR2*DIM*2);  // embeddings -> layer-2 agg/out
  unsigned short* x2   = (unsigned short*)alloc((size_t)NR2*DIM*2);  // slab -> layer-1 out (silu'd)
  unsigned short* agg1 = (unsigned short*)alloc((size_t)RN*DIM*2);   // go agg -> layer-2 item out
  if (off > ws_size) return;  // visible as absmax == 5.8125

  unsigned int* slab = (unsigned int*)x2;   // 8MB alias; dead after buildCSR3

  unsigned short* x1u = x1;
  unsigned short* x1i = x1 + (size_t)RN*DIM;
  unsigned short* x2u = x2;
  unsigned short* x2i = x2 + (size_t)RN*DIM;

  const int G8A = (NR2*DIM/8)/256;          // 12500
  const int GSU = NR2/16;                   // 25000 blocks: union spmm, 4 rows/wave

  float* b_go1 = params + 12288;
  float* b_bk1 = params + 24640;
  float* b_go2 = params + 36992;
  float* b_bk2 = params + 49344;
  float* g1u = params + 49408; float* be1u = params + 49472;
  float* g1i = params + 49536; float* be1i = params + 49600;
  float* g2u = params + 49664; float* be2u = params + 49728;
  float* g2i = params + 49792; float* be2i = params + 49856;

  Ptrs16 ps;
  for (int i = 0; i < 16; ++i) ps.p[i] = d_in[2+i];

  detect2_k<<<1,256,0,stream>>>((const unsigned short*)user_emb, (const unsigned int*)go_src,
                                flags, ps, params, stats);
  convpp_k<<<G8A + 128,256,0,stream>>>(user_emb, item_emb, x1, ps, wpack, flags, NR2*DIM/8);

  // ---- CSR build ----
  pass12_k<<<NBLK,256,0,stream>>>((const unsigned int*)go_src, (const unsigned int*)go_dst,
                                  (const unsigned int*)back_src, (const unsigned int*)back_dst,
                                  Cmat, Rloc, slab, flags);
  sizes_k<<<(NBB+3)/4,256,0,stream>>>(Cmat, Sbuf);
  scanS_k<<<1,1024,0,stream>>>(Sbuf, s0g, rs_all);
  buildCSR3_k<<<NBB,512,0,stream>>>(Cmat, Rloc, s0g, slab, rs_all, col_all);

  // ---- layer 1: one union spmm (go rows -> agg1, back rows -> x2u scratch),
  //      one merged gemm (go: agg1+x1i -> x2i; back: x2u+x1u -> x2u in-place) ----
  spmmU_k<<<GSU,256,0,stream>>>(rs_all, col_all, x1, agg1, x2u);
  {
    GemmCfg go1{agg1, x1i, wpack + 0*8192, b_go1, x2i, stats + 0};
    GemmCfg bk1{x2u,  x1u, wpack + 1*8192, b_bk1, x2u, stats + 128};
    gemm2m_k<<<1024,256,0,stream>>>(go1, bk1);
  }
  bnfin2_k<<<1,128,0,stream>>>(stats + 0, g1i, be1i, bnac + 0, g1u, be1u, bnac + 128);
  bnapply2_k<<<G8A,256,0,stream>>>(x2, bnac + 128, bnac + 0, NR2*DIM/8);

  // ---- layer 2: union spmm from silu'd x2 -> agg2 = x1 (union),
  //      merged gemm (go: x1lo+x2i -> agg1; back: x1hi+x2u -> x1hi in-place) ----
  spmmU_k<<<GSU,256,0,stream>>>(rs_all, col_all, x2, x1u, x1i);
  {
    GemmCfg go2{x1u, x2i, wpack + 2*8192, b_go2, agg1, stats + 256};
    GemmCfg bk2{x1i, x2u, wpack + 3*8192, b_bk2, x1i,  stats + 384};
    gemm2m_k<<<1024,256,0,stream>>>(go2, bk2);
  }
  bnfin2_k<<<1,128,0,stream>>>(stats + 256, g2i, be2i, bnac + 256, g2u, be2u, bnac + 384);
  bnout2_k<<<G8A,256,0,stream>>>(x1i, agg1, bnac + 384, bnac + 256, d_out, flags, NR2*DIM/8);
}